// Round 1
// baseline (895.659 us; speedup 1.0000x reference)
//
#include <hip/hip_runtime.h>
#include <math.h>

#define N_NODES 100000
#define N_EDGES 1600000
#define IN_F 512
#define HID 128
#define NCLS 7

// ---------------- degree / dinv ----------------
__global__ void k_deg_count(const int* __restrict__ ei, const float* __restrict__ ew,
                            float* __restrict__ degf, int* __restrict__ cnt) {
  int e = blockIdx.x * blockDim.x + threadIdx.x;
  if (e >= N_EDGES) return;
  int d = ei[N_EDGES + e];
  atomicAdd(&degf[d], ew[e]);
  atomicAdd(&cnt[d], 1);
}

__global__ void k_dinv(const float* __restrict__ degf, float* __restrict__ dinv) {
  int i = blockIdx.x * blockDim.x + threadIdx.x;
  if (i >= N_NODES) return;
  dinv[i] = rsqrtf(degf[i] + 1.0f);  // +1 = self-loop weight; deg always > 0
}

// ---------------- exclusive prefix scan over cnt[N] -> offs[N] ----------------
__global__ void k_scan_partial(const int* __restrict__ cnt, int* __restrict__ bsum) {
  __shared__ int s[256];
  int t = threadIdx.x;
  int base = blockIdx.x * 1024;
  int v = 0;
#pragma unroll
  for (int q = 0; q < 4; q++) {
    int idx = base + t * 4 + q;
    if (idx < N_NODES) v += cnt[idx];
  }
  s[t] = v;
  __syncthreads();
  for (int o = 128; o > 0; o >>= 1) {
    if (t < o) s[t] += s[t + o];
    __syncthreads();
  }
  if (t == 0) bsum[blockIdx.x] = s[0];
}

__global__ void k_scan_bsum(int* bsum, int nb) {
  if (threadIdx.x == 0 && blockIdx.x == 0) {
    int acc = 0;
    for (int i = 0; i < nb; i++) { int v = bsum[i]; bsum[i] = acc; acc += v; }
  }
}

__global__ void k_scan_final(const int* __restrict__ cnt, const int* __restrict__ bsum,
                             int* __restrict__ offs) {
  __shared__ int s[256];
  int t = threadIdx.x;
  int base = blockIdx.x * 1024;
  int v[4]; int sum = 0;
#pragma unroll
  for (int q = 0; q < 4; q++) {
    int idx = base + t * 4 + q;
    v[q] = (idx < N_NODES) ? cnt[idx] : 0;
    sum += v[q];
  }
  s[t] = sum;
  __syncthreads();
  for (int o = 1; o < 256; o <<= 1) {   // Hillis-Steele inclusive scan
    int x = (t >= o) ? s[t - o] : 0;
    __syncthreads();
    s[t] += x;
    __syncthreads();
  }
  int acc = s[t] - sum + bsum[blockIdx.x];  // exclusive prefix for this thread
#pragma unroll
  for (int q = 0; q < 4; q++) {
    int idx = base + t * 4 + q;
    if (idx < N_NODES) offs[idx] = acc;
    acc += v[q];
  }
}

// ---------------- CSR fill (bucket by dst), norm precomputed ----------------
__global__ void k_fill(const int* __restrict__ ei, const float* __restrict__ ew,
                       const float* __restrict__ dinv, const int* __restrict__ offs,
                       int* __restrict__ cursor, int* __restrict__ csr_src,
                       float* __restrict__ csr_norm) {
  int e = blockIdx.x * blockDim.x + threadIdx.x;
  if (e >= N_EDGES) return;
  int sidx = ei[e];
  int d = ei[N_EDGES + e];
  float nrm = dinv[sidx] * ew[e] * dinv[d];
  int p = offs[d] + atomicAdd(&cursor[d], 1);
  csr_src[p] = sidx;
  csr_norm[p] = nrm;
}

// ---------------- GEMM1: h[N,128] = x[N,512] @ W1[512,128], fp32 tiled ----------------
#define BM 64
#define BK 32
__global__ __launch_bounds__(256) void k_gemm1(const float* __restrict__ x,
                                               const float* __restrict__ W1,
                                               float* __restrict__ h) {
  __shared__ float As[BK][BM];     // transposed: [k][m] -> vector reads in m
  __shared__ float Bs[BK][HID];    // [k][n]
  const int tid = threadIdx.x;
  const int tx = tid & 31;         // n-quad index (n = tx*4..tx*4+3)
  const int ty = tid >> 5;         // m-oct index  (m = ty*8..ty*8+7)
  const int m0 = blockIdx.x * BM;

  float acc[8][4];
#pragma unroll
  for (int i = 0; i < 8; i++)
#pragma unroll
    for (int j = 0; j < 4; j++) acc[i][j] = 0.0f;

  for (int k0 = 0; k0 < IN_F; k0 += BK) {
#pragma unroll
    for (int q = 0; q < 2; q++) {          // 512 float4s of A-tile, 2 per thread
      int idx = tid * 2 + q;               // 0..511
      int row = idx >> 3;                  // 0..63
      int c4  = idx & 7;                   // 0..7
      int gr = m0 + row;
      float4 v = make_float4(0.f, 0.f, 0.f, 0.f);
      if (gr < N_NODES) v = *(const float4*)(x + (size_t)gr * IN_F + k0 + c4 * 4);
      As[c4 * 4 + 0][row] = v.x;
      As[c4 * 4 + 1][row] = v.y;
      As[c4 * 4 + 2][row] = v.z;
      As[c4 * 4 + 3][row] = v.w;
    }
#pragma unroll
    for (int j = 0; j < 4; j++) {          // 1024 float4s of B-tile, 4 per thread
      int idx = tid + j * 256;             // 0..1023
      int row = idx >> 5;                  // 0..31
      int c4  = idx & 31;                  // 0..31
      *(float4*)(&Bs[row][c4 * 4]) = *(const float4*)(W1 + (size_t)(k0 + row) * HID + c4 * 4);
    }
    __syncthreads();
#pragma unroll
    for (int kk = 0; kk < BK; kk++) {
      float a[8], b[4];
      *(float4*)(a)     = *(const float4*)(&As[kk][ty * 8]);
      *(float4*)(a + 4) = *(const float4*)(&As[kk][ty * 8 + 4]);
      *(float4*)(b)     = *(const float4*)(&Bs[kk][tx * 4]);
#pragma unroll
      for (int i = 0; i < 8; i++)
#pragma unroll
        for (int j = 0; j < 4; j++) acc[i][j] = fmaf(a[i], b[j], acc[i][j]);
    }
    __syncthreads();
  }
#pragma unroll
  for (int i = 0; i < 8; i++) {
    int gr = m0 + ty * 8 + i;
    if (gr < N_NODES)
      *(float4*)(h + (size_t)gr * HID + tx * 4) =
          make_float4(acc[i][0], acc[i][1], acc[i][2], acc[i][3]);
  }
}

// ---------------- layer-1 aggregation: wave per dst node, no atomics ----------------
__global__ __launch_bounds__(256) void k_agg1(const float* __restrict__ h,
    const float* __restrict__ dinv, const int* __restrict__ offs, const int* __restrict__ cnt,
    const int* __restrict__ csr_src, const float* __restrict__ csr_norm,
    const float* __restrict__ b1, float* __restrict__ act1) {
  int i = blockIdx.x * 4 + (threadIdx.x >> 6);   // wave -> node
  int lane = threadIdx.x & 63;                   // lane covers feats [2l, 2l+1]
  if (i >= N_NODES) return;
  int start = offs[i], len = cnt[i];
  float ax = 0.f, ay = 0.f;
  for (int p = start; p < start + len; p++) {
    int s = csr_src[p];
    float nrm = csr_norm[p];
    float2 hv = *(const float2*)(h + (size_t)s * HID + lane * 2);
    ax = fmaf(hv.x, nrm, ax);
    ay = fmaf(hv.y, nrm, ay);
  }
  float di = dinv[i], sn = di * di;              // self-loop norm
  float2 hv = *(const float2*)(h + (size_t)i * HID + lane * 2);
  ax = fmaf(hv.x, sn, ax);
  ay = fmaf(hv.y, sn, ay);
  float2 bb = *(const float2*)(b1 + lane * 2);
  float vx = ax + bb.x, vy = ay + bb.y;
  vx = vx > 0.f ? vx : expm1f(vx);               // ELU (alpha=1)
  vy = vy > 0.f ? vy : expm1f(vy);
  *(float2*)(act1 + (size_t)i * HID + lane * 2) = make_float2(vx, vy);
}

// ---------------- GEMM2: h2[N,8(pad)] = act1[N,128] @ W2[128,7] ----------------
__global__ __launch_bounds__(256) void k_gemm2(const float* __restrict__ act1,
                                               const float* __restrict__ W2,
                                               float* __restrict__ h2) {
  __shared__ float sA[32][HID + 1];   // +1 pad: breaks 32-way bank aliasing on row reads
  __shared__ float sW[HID * NCLS];    // 896 floats
  const int tid = threadIdx.x;
  const int r0 = blockIdx.x * 32;
#pragma unroll
  for (int j = 0; j < 4; j++) {
    int idx = tid + j * 256;          // 0..1023
    int row = idx >> 5;               // 0..31
    int c4  = idx & 31;
    float4 v = *(const float4*)(act1 + (size_t)(r0 + row) * HID + c4 * 4);
    sA[row][c4 * 4 + 0] = v.x; sA[row][c4 * 4 + 1] = v.y;
    sA[row][c4 * 4 + 2] = v.z; sA[row][c4 * 4 + 3] = v.w;
  }
#pragma unroll
  for (int j = 0; j < 4; j++) {
    int idx = tid + j * 256;
    if (idx < HID * NCLS) sW[idx] = W2[idx];
  }
  __syncthreads();
  const int r = tid >> 3;             // 0..31
  const int c = tid & 7;              // 0..7 (c==7 writes the zero pad column)
  float acc = 0.0f;
  if (c < NCLS) {
#pragma unroll 8
    for (int k = 0; k < HID; k++) acc = fmaf(sA[r][k], sW[k * NCLS + c], acc);
  }
  h2[(size_t)(r0 + r) * 8 + c] = acc;
}

// ---------------- layer-2 aggregation + bias + log_softmax fused ----------------
__global__ __launch_bounds__(256) void k_agg2(const float* __restrict__ h2,
    const float* __restrict__ dinv, const int* __restrict__ offs, const int* __restrict__ cnt,
    const int* __restrict__ csr_src, const float* __restrict__ csr_norm,
    const float* __restrict__ b2, float* __restrict__ out) {
  int tid = threadIdx.x;
  int i = blockIdx.x * 32 + (tid >> 3);   // 8 lanes per node
  int f = tid & 7;                        // f==7 is padding lane (reads zeros)
  if (i >= N_NODES) return;
  int start = offs[i], len = cnt[i];
  float acc = 0.0f;
  for (int p = start; p < start + len; p++) {
    int s = csr_src[p];
    float nrm = csr_norm[p];
    acc += h2[(size_t)s * 8 + f] * nrm;
  }
  float di = dinv[i];
  acc += h2[(size_t)i * 8 + f] * di * di;
  float v = acc + ((f < NCLS) ? b2[f] : 0.0f);
  float vm = (f < NCLS) ? v : -INFINITY;
#pragma unroll
  for (int o = 1; o < 8; o <<= 1) vm = fmaxf(vm, __shfl_xor(vm, o, 8));
  float ex = (f < NCLS) ? expf(v - vm) : 0.0f;
  float s8 = ex;
#pragma unroll
  for (int o = 1; o < 8; o <<= 1) s8 += __shfl_xor(s8, o, 8);
  float lse = logf(s8);
  if (f < NCLS) out[(size_t)i * NCLS + f] = v - vm - lse;
}

// ---------------- launch ----------------
extern "C" void kernel_launch(void* const* d_in, const int* in_sizes, int n_in,
                              void* d_out, int out_size, void* d_ws, size_t ws_size,
                              hipStream_t stream) {
  const float* x  = (const float*)d_in[0];
  const int*   ei = (const int*)d_in[1];
  const float* ew = (const float*)d_in[2];
  const float* W1 = (const float*)d_in[3];
  const float* b1 = (const float*)d_in[4];
  const float* W2 = (const float*)d_in[5];
  const float* b2 = (const float*)d_in[6];
  float* out = (float*)d_out;

  char* w = (char*)d_ws;
  const size_t Npad = ((size_t)N_NODES * 4 + 255) & ~(size_t)255;
  const size_t Epad = ((size_t)N_EDGES * 4 + 255) & ~(size_t)255;
  size_t off = 0;
  int*   cnt      = (int*)(w + off);   off += Npad;   // \  zeroed together
  int*   cursor   = (int*)(w + off);   off += Npad;   //  | (contiguous region)
  float* degf     = (float*)(w + off); off += Npad;   // /
  float* dinv     = (float*)(w + off); off += Npad;
  int*   offs     = (int*)(w + off);   off += Npad;
  int*   bsum     = (int*)(w + off);   off += 1024;
  int*   csr_src  = (int*)(w + off);   off += Epad;
  float* csr_norm = (float*)(w + off); off += Epad;
  float* h        = (float*)(w + off); off += (size_t)N_NODES * HID * 4;
  float* act1     = (float*)(w + off); off += (size_t)N_NODES * HID * 4;
  float* h2       = (float*)(w + off); off += (size_t)N_NODES * 8 * 4;

  // zero cnt / cursor / degf in one memset (ws is poisoned 0xAA before each call)
  hipMemsetAsync(cnt, 0, 3 * Npad, stream);

  k_deg_count<<<N_EDGES / 256, 256, 0, stream>>>(ei, ew, degf, cnt);
  k_dinv<<<(N_NODES + 255) / 256, 256, 0, stream>>>(degf, dinv);
  const int nb = (N_NODES + 1023) / 1024;   // 98
  k_scan_partial<<<nb, 256, 0, stream>>>(cnt, bsum);
  k_scan_bsum<<<1, 64, 0, stream>>>(bsum, nb);
  k_scan_final<<<nb, 256, 0, stream>>>(cnt, bsum, offs);
  k_fill<<<N_EDGES / 256, 256, 0, stream>>>(ei, ew, dinv, offs, cursor, csr_src, csr_norm);
  k_gemm1<<<(N_NODES + BM - 1) / BM, 256, 0, stream>>>(x, W1, h);
  k_agg1<<<(N_NODES + 3) / 4, 256, 0, stream>>>(h, dinv, offs, cnt, csr_src, csr_norm, b1, act1);
  k_gemm2<<<N_NODES / 32, 256, 0, stream>>>(act1, W2, h2);
  k_agg2<<<N_NODES / 32, 256, 0, stream>>>(h2, dinv, offs, cnt, csr_src, csr_norm, b2, out);
}

// Round 2
// 826.027 us; speedup vs baseline: 1.0843x; 1.0843x over previous
//
#include <hip/hip_runtime.h>
#include <hip/hip_bf16.h>
#include <math.h>

#define N_NODES 100000
#define N_EDGES 1600000
#define IN_F 512
#define HID 128
#define NCLS 7

typedef short short8 __attribute__((ext_vector_type(8)));
typedef float f32x4 __attribute__((ext_vector_type(4)));

__device__ __forceinline__ unsigned pack_bf16x2(float a, float b) {
  unsigned ua = __float_as_uint(a), ub = __float_as_uint(b);
  unsigned ra = (ua + 0x7FFFu + ((ua >> 16) & 1u)) >> 16;     // RNE
  unsigned rb = (ub + 0x7FFFu + ((ub >> 16) & 1u)) >> 16;
  return ra | (rb << 16);
}
__device__ __forceinline__ unsigned short f32_to_bf16(float v) {
  unsigned u = __float_as_uint(v);
  return (unsigned short)((u + 0x7FFFu + ((u >> 16) & 1u)) >> 16);
}

// ---------------- degree / dinv ----------------
__global__ void k_deg_count(const int* __restrict__ ei, const float* __restrict__ ew,
                            float* __restrict__ degf, int* __restrict__ cnt) {
  int e = blockIdx.x * blockDim.x + threadIdx.x;
  if (e >= N_EDGES) return;
  int d = ei[N_EDGES + e];
  atomicAdd(&degf[d], ew[e]);
  atomicAdd(&cnt[d], 1);
}

__global__ void k_dinv(const float* __restrict__ degf, float* __restrict__ dinv) {
  int i = blockIdx.x * blockDim.x + threadIdx.x;
  if (i >= N_NODES) return;
  dinv[i] = rsqrtf(degf[i] + 1.0f);  // +1 = self-loop weight
}

// ---------------- W1 [512][128] f32 -> W1bT [128][512] bf16 (transposed) ----------------
__global__ void k_w1t(const float* __restrict__ W1, unsigned* __restrict__ w1t_u) {
  int n = blockIdx.x;        // 0..127
  int t = threadIdx.x;       // 0..255 -> k pair 2t, 2t+1
  float a = W1[(size_t)(2 * t) * HID + n];
  float b = W1[(size_t)(2 * t + 1) * HID + n];
  w1t_u[(size_t)n * 256 + t] = pack_bf16x2(a, b);
}

// ---------------- exclusive prefix scan over cnt[N] -> offs[N] ----------------
__global__ void k_scan_partial(const int* __restrict__ cnt, int* __restrict__ bsum) {
  __shared__ int s[256];
  int t = threadIdx.x;
  int base = blockIdx.x * 1024;
  int v = 0;
#pragma unroll
  for (int q = 0; q < 4; q++) {
    int idx = base + t * 4 + q;
    if (idx < N_NODES) v += cnt[idx];
  }
  s[t] = v;
  __syncthreads();
  for (int o = 128; o > 0; o >>= 1) {
    if (t < o) s[t] += s[t + o];
    __syncthreads();
  }
  if (t == 0) bsum[blockIdx.x] = s[0];
}

__global__ void k_scan_bsum(int* bsum, int nb) {
  if (threadIdx.x == 0 && blockIdx.x == 0) {
    int acc = 0;
    for (int i = 0; i < nb; i++) { int v = bsum[i]; bsum[i] = acc; acc += v; }
  }
}

__global__ void k_scan_final(const int* __restrict__ cnt, const int* __restrict__ bsum,
                             int* __restrict__ offs) {
  __shared__ int s[256];
  int t = threadIdx.x;
  int base = blockIdx.x * 1024;
  int v[4]; int sum = 0;
#pragma unroll
  for (int q = 0; q < 4; q++) {
    int idx = base + t * 4 + q;
    v[q] = (idx < N_NODES) ? cnt[idx] : 0;
    sum += v[q];
  }
  s[t] = sum;
  __syncthreads();
  for (int o = 1; o < 256; o <<= 1) {
    int x = (t >= o) ? s[t - o] : 0;
    __syncthreads();
    s[t] += x;
    __syncthreads();
  }
  int acc = s[t] - sum + bsum[blockIdx.x];
#pragma unroll
  for (int q = 0; q < 4; q++) {
    int idx = base + t * 4 + q;
    if (idx < N_NODES) offs[idx] = acc;
    acc += v[q];
  }
}

// ---------------- CSR fill (bucket by dst), norm precomputed ----------------
__global__ void k_fill(const int* __restrict__ ei, const float* __restrict__ ew,
                       const float* __restrict__ dinv, const int* __restrict__ offs,
                       int* __restrict__ cursor, int* __restrict__ csr_src,
                       float* __restrict__ csr_norm) {
  int e = blockIdx.x * blockDim.x + threadIdx.x;
  if (e >= N_EDGES) return;
  int sidx = ei[e];
  int d = ei[N_EDGES + e];
  float nrm = dinv[sidx] * ew[e] * dinv[d];
  int p = offs[d] + atomicAdd(&cursor[d], 1);
  csr_src[p] = sidx;
  csr_norm[p] = nrm;
}

// ---------------- GEMM1 (MFMA bf16): h_bf16[N,128] = bf16(x[N,512]) @ bf16(W1) ----------------
// 128x128 block tile, BK=32, 4 waves in 2x2 quadrants, 16x16x32 MFMA.
// LDS rows padded to 80 B (20 dwords) -> conflict-free ds_read_b128 fragments.
#define G1_LDSROW 20   // dwords per LDS tile row (16 data + 4 pad)
__global__ __launch_bounds__(256) void k_gemm1(const float* __restrict__ x,
                                               const unsigned* __restrict__ w1t_u,
                                               unsigned short* __restrict__ h_u16) {
  __shared__ unsigned As[128 * G1_LDSROW];  // A tile: 128 rows x 32 bf16 (padded)
  __shared__ unsigned Bs[128 * G1_LDSROW];  // B tile: 128 n-rows x 32 bf16 (padded)
  const int tid = threadIdx.x;
  const int lane = tid & 63;
  const int w = tid >> 6;           // wave 0..3
  const int wr = w >> 1, wc = w & 1;
  const int quad = lane >> 4;       // 0..3
  const int l16 = lane & 15;
  const int m0 = blockIdx.x * 128;

  f32x4 acc[4][4];
#pragma unroll
  for (int i = 0; i < 4; i++)
#pragma unroll
    for (int j = 0; j < 4; j++) acc[i][j] = (f32x4){0.f, 0.f, 0.f, 0.f};

  for (int k0 = 0; k0 < IN_F; k0 += 32) {
    __syncthreads();   // previous iteration's fragment reads complete
    // ---- stage A: x[m0..m0+127][k0..k0+31] f32 -> bf16 LDS ----
#pragma unroll
    for (int q = 0; q < 4; q++) {
      int flat = q * 256 + tid;        // 0..1023 float4 slots (128 rows x 8)
      int row = flat >> 3;
      int c4 = flat & 7;               // float4 index within row (32 f32 = 8 f4)
      int gr = m0 + row;
      float4 v = make_float4(0.f, 0.f, 0.f, 0.f);
      if (gr < N_NODES) v = *(const float4*)(x + (size_t)gr * IN_F + k0 + c4 * 4);
      unsigned lo = pack_bf16x2(v.x, v.y);
      unsigned hi = pack_bf16x2(v.z, v.w);
      *(uint2*)&As[row * G1_LDSROW + c4 * 2] = make_uint2(lo, hi);
    }
    // ---- stage B: W1bT[n=0..127][k0..k0+31] bf16 (already packed) ----
#pragma unroll
    for (int q = 0; q < 2; q++) {
      int flat = q * 256 + tid;        // 0..511 uint4 slots (128 rows x 4)
      int row = flat >> 2;
      int c = flat & 3;
      uint4 bv = ((const uint4*)w1t_u)[(size_t)row * 64 + (k0 >> 3) + c];
      *(uint4*)&Bs[row * G1_LDSROW + c * 4] = bv;
    }
    __syncthreads();
    // ---- fragments + MFMA ----
    short8 af[4], bf[4];
#pragma unroll
    for (int mi = 0; mi < 4; mi++)
      af[mi] = *(const short8*)&As[(wr * 64 + mi * 16 + l16) * G1_LDSROW + quad * 4];
#pragma unroll
    for (int ni = 0; ni < 4; ni++)
      bf[ni] = *(const short8*)&Bs[(wc * 64 + ni * 16 + l16) * G1_LDSROW + quad * 4];
#pragma unroll
    for (int mi = 0; mi < 4; mi++)
#pragma unroll
      for (int ni = 0; ni < 4; ni++)
        acc[mi][ni] = __builtin_amdgcn_mfma_f32_16x16x32_bf16(af[mi], bf[ni], acc[mi][ni], 0, 0, 0);
  }
  // ---- epilogue: C/D layout col=lane&15, row=quad*4+reg; store bf16 ----
#pragma unroll
  for (int mi = 0; mi < 4; mi++) {
#pragma unroll
    for (int ni = 0; ni < 4; ni++) {
      int gcol = wc * 64 + ni * 16 + l16;
#pragma unroll
      for (int r = 0; r < 4; r++) {
        int grow = m0 + wr * 64 + mi * 16 + quad * 4 + r;
        if (grow < N_NODES)
          h_u16[(size_t)grow * HID + gcol] = f32_to_bf16(acc[mi][ni][r]);
      }
    }
  }
}

// ---------------- layer-1 aggregation: wave per dst node, bf16 h, no atomics ----------------
__global__ __launch_bounds__(256) void k_agg1(const unsigned* __restrict__ h_u,
    const float* __restrict__ dinv, const int* __restrict__ offs, const int* __restrict__ cnt,
    const int* __restrict__ csr_src, const float* __restrict__ csr_norm,
    const float* __restrict__ b1, unsigned* __restrict__ act1_u) {
  int i = blockIdx.x * 4 + (threadIdx.x >> 6);   // wave -> node
  int lane = threadIdx.x & 63;                   // lane covers feats [2l, 2l+1]
  if (i >= N_NODES) return;
  int start = offs[i], len = cnt[i];
  float ax = 0.f, ay = 0.f;
  for (int p = start; p < start + len; p++) {
    int s = csr_src[p];
    float nrm = csr_norm[p];
    unsigned u = h_u[(size_t)s * 64 + lane];
    ax = fmaf(__uint_as_float(u << 16), nrm, ax);
    ay = fmaf(__uint_as_float(u & 0xFFFF0000u), nrm, ay);
  }
  float di = dinv[i], sn = di * di;              // self-loop norm
  unsigned u = h_u[(size_t)i * 64 + lane];
  ax = fmaf(__uint_as_float(u << 16), sn, ax);
  ay = fmaf(__uint_as_float(u & 0xFFFF0000u), sn, ay);
  float2 bb = *(const float2*)(b1 + lane * 2);
  float vx = ax + bb.x, vy = ay + bb.y;
  vx = vx > 0.f ? vx : expm1f(vx);               // ELU (alpha=1)
  vy = vy > 0.f ? vy : expm1f(vy);
  act1_u[(size_t)i * 64 + lane] = pack_bf16x2(vx, vy);
}

// ---------------- GEMM2: h2[N,8(pad)] = act1_bf16[N,128] @ W2[128,7] ----------------
__global__ __launch_bounds__(256) void k_gemm2(const unsigned* __restrict__ act1_u,
                                               const float* __restrict__ W2,
                                               float* __restrict__ h2) {
  __shared__ float sA[32][HID + 1];
  __shared__ float sW[HID * NCLS];
  const int tid = threadIdx.x;
  const int r0 = blockIdx.x * 32;
#pragma unroll
  for (int j = 0; j < 8; j++) {
    int idx = tid + j * 256;          // 0..2047 uints (32 rows x 64)
    int row = idx >> 6;
    int c = idx & 63;
    unsigned u = act1_u[(size_t)(r0 + row) * 64 + c];
    sA[row][c * 2]     = __uint_as_float(u << 16);
    sA[row][c * 2 + 1] = __uint_as_float(u & 0xFFFF0000u);
  }
#pragma unroll
  for (int j = 0; j < 4; j++) {
    int idx = tid + j * 256;
    if (idx < HID * NCLS) sW[idx] = W2[idx];
  }
  __syncthreads();
  const int r = tid >> 3;
  const int c = tid & 7;
  float acc = 0.0f;
  if (c < NCLS) {
#pragma unroll 8
    for (int k = 0; k < HID; k++) acc = fmaf(sA[r][k], sW[k * NCLS + c], acc);
  }
  h2[(size_t)(r0 + r) * 8 + c] = acc;
}

// ---------------- layer-2 aggregation + bias + log_softmax fused ----------------
__global__ __launch_bounds__(256) void k_agg2(const float* __restrict__ h2,
    const float* __restrict__ dinv, const int* __restrict__ offs, const int* __restrict__ cnt,
    const int* __restrict__ csr_src, const float* __restrict__ csr_norm,
    const float* __restrict__ b2, float* __restrict__ out) {
  int tid = threadIdx.x;
  int i = blockIdx.x * 32 + (tid >> 3);   // 8 lanes per node
  int f = tid & 7;                        // f==7 is padding lane
  if (i >= N_NODES) return;
  int start = offs[i], len = cnt[i];
  float acc = 0.0f;
  for (int p = start; p < start + len; p++) {
    int s = csr_src[p];
    float nrm = csr_norm[p];
    acc += h2[(size_t)s * 8 + f] * nrm;
  }
  float di = dinv[i];
  acc += h2[(size_t)i * 8 + f] * di * di;
  float v = acc + ((f < NCLS) ? b2[f] : 0.0f);
  float vm = (f < NCLS) ? v : -INFINITY;
#pragma unroll
  for (int o = 1; o < 8; o <<= 1) vm = fmaxf(vm, __shfl_xor(vm, o, 8));
  float ex = (f < NCLS) ? expf(v - vm) : 0.0f;
  float s8 = ex;
#pragma unroll
  for (int o = 1; o < 8; o <<= 1) s8 += __shfl_xor(s8, o, 8);
  float lse = logf(s8);
  if (f < NCLS) out[(size_t)i * NCLS + f] = v - vm - lse;
}

// ---------------- launch ----------------
extern "C" void kernel_launch(void* const* d_in, const int* in_sizes, int n_in,
                              void* d_out, int out_size, void* d_ws, size_t ws_size,
                              hipStream_t stream) {
  const float* x  = (const float*)d_in[0];
  const int*   ei = (const int*)d_in[1];
  const float* ew = (const float*)d_in[2];
  const float* W1 = (const float*)d_in[3];
  const float* b1 = (const float*)d_in[4];
  const float* W2 = (const float*)d_in[5];
  const float* b2 = (const float*)d_in[6];
  float* out = (float*)d_out;

  char* w = (char*)d_ws;
  const size_t Npad = ((size_t)N_NODES * 4 + 255) & ~(size_t)255;
  const size_t Epad = ((size_t)N_EDGES * 4 + 255) & ~(size_t)255;
  size_t off = 0;
  int*      cnt      = (int*)(w + off);      off += Npad;   // \  zeroed together
  int*      cursor   = (int*)(w + off);      off += Npad;   //  | (contiguous)
  float*    degf     = (float*)(w + off);    off += Npad;   // /
  float*    dinv     = (float*)(w + off);    off += Npad;
  int*      offs     = (int*)(w + off);      off += Npad;
  int*      bsum     = (int*)(w + off);      off += 1024;
  int*      csr_src  = (int*)(w + off);      off += Epad;
  float*    csr_norm = (float*)(w + off);    off += Epad;
  unsigned* w1t_u    = (unsigned*)(w + off); off += (size_t)HID * 256 * 4;       // 128 KB
  unsigned short* h_u16 = (unsigned short*)(w + off); off += (size_t)N_NODES * HID * 2;
  unsigned* act1_u   = (unsigned*)(w + off); off += (size_t)N_NODES * 64 * 4;
  float*    h2       = (float*)(w + off);    off += (size_t)N_NODES * 8 * 4;

  hipMemsetAsync(cnt, 0, 3 * Npad, stream);

  k_deg_count<<<N_EDGES / 256, 256, 0, stream>>>(ei, ew, degf, cnt);
  k_w1t<<<HID, 256, 0, stream>>>(W1, w1t_u);
  k_dinv<<<(N_NODES + 255) / 256, 256, 0, stream>>>(degf, dinv);
  const int nb = (N_NODES + 1023) / 1024;
  k_scan_partial<<<nb, 256, 0, stream>>>(cnt, bsum);
  k_scan_bsum<<<1, 64, 0, stream>>>(bsum, nb);
  k_scan_final<<<nb, 256, 0, stream>>>(cnt, bsum, offs);
  k_fill<<<N_EDGES / 256, 256, 0, stream>>>(ei, ew, dinv, offs, cursor, csr_src, csr_norm);
  k_gemm1<<<(N_NODES + 127) / 128, 256, 0, stream>>>(x, w1t_u, h_u16);
  k_agg1<<<(N_NODES + 3) / 4, 256, 0, stream>>>((const unsigned*)h_u16, dinv, offs, cnt,
                                                csr_src, csr_norm, b1, act1_u);
  k_gemm2<<<N_NODES / 32, 256, 0, stream>>>(act1_u, W2, h2);
  k_agg2<<<N_NODES / 32, 256, 0, stream>>>(h2, dinv, offs, cnt, csr_src, csr_norm, b2, out);
}

// Round 3
// 699.819 us; speedup vs baseline: 1.2798x; 1.1803x over previous
//
#include <hip/hip_runtime.h>
#include <hip/hip_bf16.h>
#include <math.h>

#define N_NODES 100000
#define N_EDGES 1600000
#define IN_F 512
#define HID 128
#define NCLS 7

typedef short short8 __attribute__((ext_vector_type(8)));
typedef float f32x4 __attribute__((ext_vector_type(4)));

__device__ __forceinline__ unsigned pack_bf16x2(float a, float b) {
  unsigned ua = __float_as_uint(a), ub = __float_as_uint(b);
  unsigned ra = (ua + 0x7FFFu + ((ua >> 16) & 1u)) >> 16;     // RNE
  unsigned rb = (ub + 0x7FFFu + ((ub >> 16) & 1u)) >> 16;
  return ra | (rb << 16);
}
__device__ __forceinline__ unsigned short f32_to_bf16(float v) {
  unsigned u = __float_as_uint(v);
  return (unsigned short)((u + 0x7FFFu + ((u >> 16) & 1u)) >> 16);
}
__device__ __forceinline__ float bf_lo(unsigned u) { return __uint_as_float(u << 16); }
__device__ __forceinline__ float bf_hi(unsigned u) { return __uint_as_float(u & 0xFFFF0000u); }

// ---------------- degree / dinv ----------------
__global__ void k_deg_count(const int* __restrict__ ei, const float* __restrict__ ew,
                            float* __restrict__ degf, int* __restrict__ cnt) {
  int e = blockIdx.x * blockDim.x + threadIdx.x;
  if (e >= N_EDGES) return;
  int d = ei[N_EDGES + e];
  atomicAdd(&degf[d], ew[e]);
  atomicAdd(&cnt[d], 1);
}

__global__ void k_dinv(const float* __restrict__ degf, float* __restrict__ dinv,
                       uint2* __restrict__ csr_pad) {
  int i = blockIdx.x * blockDim.x + threadIdx.x;
  if (i < 8) csr_pad[i] = make_uint2(0u, 0u);   // safe over-read entries (src=0, norm=0)
  if (i >= N_NODES) return;
  dinv[i] = rsqrtf(degf[i] + 1.0f);  // +1 = self-loop weight
}

// ---------------- W1 [512][128] f32 -> W1bT [128][512] bf16 (transposed) ----------------
__global__ void k_w1t(const float* __restrict__ W1, unsigned* __restrict__ w1t_u) {
  int n = blockIdx.x;        // 0..127
  int t = threadIdx.x;       // 0..255 -> k pair 2t, 2t+1
  float a = W1[(size_t)(2 * t) * HID + n];
  float b = W1[(size_t)(2 * t + 1) * HID + n];
  w1t_u[(size_t)n * 256 + t] = pack_bf16x2(a, b);
}

// ---------------- exclusive prefix scan over cnt[N] -> offs[N] ----------------
__global__ void k_scan_partial(const int* __restrict__ cnt, int* __restrict__ bsum) {
  __shared__ int s[256];
  int t = threadIdx.x;
  int base = blockIdx.x * 1024;
  int v = 0;
#pragma unroll
  for (int q = 0; q < 4; q++) {
    int idx = base + t * 4 + q;
    if (idx < N_NODES) v += cnt[idx];
  }
  s[t] = v;
  __syncthreads();
  for (int o = 128; o > 0; o >>= 1) {
    if (t < o) s[t] += s[t + o];
    __syncthreads();
  }
  if (t == 0) bsum[blockIdx.x] = s[0];
}

__global__ void k_scan_bsum(int* bsum, int nb) {
  if (threadIdx.x == 0 && blockIdx.x == 0) {
    int acc = 0;
    for (int i = 0; i < nb; i++) { int v = bsum[i]; bsum[i] = acc; acc += v; }
  }
}

__global__ void k_scan_final(const int* __restrict__ cnt, const int* __restrict__ bsum,
                             int* __restrict__ offs) {
  __shared__ int s[256];
  int t = threadIdx.x;
  int base = blockIdx.x * 1024;
  int v[4]; int sum = 0;
#pragma unroll
  for (int q = 0; q < 4; q++) {
    int idx = base + t * 4 + q;
    v[q] = (idx < N_NODES) ? cnt[idx] : 0;
    sum += v[q];
  }
  s[t] = sum;
  __syncthreads();
  for (int o = 1; o < 256; o <<= 1) {
    int x = (t >= o) ? s[t - o] : 0;
    __syncthreads();
    s[t] += x;
    __syncthreads();
  }
  int acc = s[t] - sum + bsum[blockIdx.x];
#pragma unroll
  for (int q = 0; q < 4; q++) {
    int idx = base + t * 4 + q;
    if (idx < N_NODES) offs[idx] = acc;
    acc += v[q];
  }
}

// ---------------- CSR fill (bucket by dst), interleaved (src,norm) ----------------
__global__ void k_fill(const int* __restrict__ ei, const float* __restrict__ ew,
                       const float* __restrict__ dinv, const int* __restrict__ offs,
                       int* __restrict__ cursor, uint2* __restrict__ csr) {
  int e = blockIdx.x * blockDim.x + threadIdx.x;
  if (e >= N_EDGES) return;
  int sidx = ei[e];
  int d = ei[N_EDGES + e];
  float nrm = dinv[sidx] * ew[e] * dinv[d];
  int p = offs[d] + atomicAdd(&cursor[d], 1);
  csr[p] = make_uint2((unsigned)sidx, __float_as_uint(nrm));   // one 8B scatter
}

// ---------------- GEMM1 (MFMA bf16): h_bf16[N,128] = bf16(x[N,512]) @ bf16(W1) ----------------
#define G1_LDSROW 20   // dwords per LDS tile row (16 data + 4 pad)
__global__ __launch_bounds__(256) void k_gemm1(const float* __restrict__ x,
                                               const unsigned* __restrict__ w1t_u,
                                               unsigned short* __restrict__ h_u16) {
  __shared__ unsigned As[128 * G1_LDSROW];
  __shared__ unsigned Bs[128 * G1_LDSROW];
  const int tid = threadIdx.x;
  const int lane = tid & 63;
  const int w = tid >> 6;
  const int wr = w >> 1, wc = w & 1;
  const int quad = lane >> 4;
  const int l16 = lane & 15;
  const int m0 = blockIdx.x * 128;

  f32x4 acc[4][4];
#pragma unroll
  for (int i = 0; i < 4; i++)
#pragma unroll
    for (int j = 0; j < 4; j++) acc[i][j] = (f32x4){0.f, 0.f, 0.f, 0.f};

  for (int k0 = 0; k0 < IN_F; k0 += 32) {
    __syncthreads();
#pragma unroll
    for (int q = 0; q < 4; q++) {
      int flat = q * 256 + tid;
      int row = flat >> 3;
      int c4 = flat & 7;
      int gr = m0 + row;
      float4 v = make_float4(0.f, 0.f, 0.f, 0.f);
      if (gr < N_NODES) v = *(const float4*)(x + (size_t)gr * IN_F + k0 + c4 * 4);
      unsigned lo = pack_bf16x2(v.x, v.y);
      unsigned hi = pack_bf16x2(v.z, v.w);
      *(uint2*)&As[row * G1_LDSROW + c4 * 2] = make_uint2(lo, hi);
    }
#pragma unroll
    for (int q = 0; q < 2; q++) {
      int flat = q * 256 + tid;
      int row = flat >> 2;
      int c = flat & 3;
      uint4 bv = ((const uint4*)w1t_u)[(size_t)row * 64 + (k0 >> 3) + c];
      *(uint4*)&Bs[row * G1_LDSROW + c * 4] = bv;
    }
    __syncthreads();
    short8 af[4], bf[4];
#pragma unroll
    for (int mi = 0; mi < 4; mi++)
      af[mi] = *(const short8*)&As[(wr * 64 + mi * 16 + l16) * G1_LDSROW + quad * 4];
#pragma unroll
    for (int ni = 0; ni < 4; ni++)
      bf[ni] = *(const short8*)&Bs[(wc * 64 + ni * 16 + l16) * G1_LDSROW + quad * 4];
#pragma unroll
    for (int mi = 0; mi < 4; mi++)
#pragma unroll
      for (int ni = 0; ni < 4; ni++)
        acc[mi][ni] = __builtin_amdgcn_mfma_f32_16x16x32_bf16(af[mi], bf[ni], acc[mi][ni], 0, 0, 0);
  }
#pragma unroll
  for (int mi = 0; mi < 4; mi++) {
#pragma unroll
    for (int ni = 0; ni < 4; ni++) {
      int gcol = wc * 64 + ni * 16 + l16;
#pragma unroll
      for (int r = 0; r < 4; r++) {
        int grow = m0 + wr * 64 + mi * 16 + quad * 4 + r;
        if (grow < N_NODES)
          h_u16[(size_t)grow * HID + gcol] = f32_to_bf16(acc[mi][ni][r]);
      }
    }
  }
}

// ---------------- layer-1 aggregation: wave/node, 4-way pipelined gathers ----------------
__global__ __launch_bounds__(256) void k_agg1(const unsigned* __restrict__ h_u,
    const float* __restrict__ dinv, const int* __restrict__ offs, const int* __restrict__ cnt,
    const uint2* __restrict__ csr, const float* __restrict__ b1,
    unsigned* __restrict__ act1_u) {
  int i = blockIdx.x * 4 + (threadIdx.x >> 6);   // wave -> node
  int lane = threadIdx.x & 63;                   // lane covers feats [2l, 2l+1]
  if (i >= N_NODES) return;
  int start = offs[i], len = cnt[i];
  int end = start + len;
  float ax = 0.f, ay = 0.f;
  for (int p = start; p < end; p += 4) {
    // 4 unconditional edge reads (csr padded with 8 zero-norm entries)
    uint2 e0 = csr[p];
    uint2 e1 = csr[p + 1];
    uint2 e2 = csr[p + 2];
    uint2 e3 = csr[p + 3];
    // 4 independent row gathers in flight
    unsigned u0 = h_u[(size_t)e0.x * 64 + lane];
    unsigned u1 = h_u[(size_t)e1.x * 64 + lane];
    unsigned u2 = h_u[(size_t)e2.x * 64 + lane];
    unsigned u3 = h_u[(size_t)e3.x * 64 + lane];
    float n0 = __uint_as_float(e0.y);
    float n1 = (p + 1 < end) ? __uint_as_float(e1.y) : 0.f;
    float n2 = (p + 2 < end) ? __uint_as_float(e2.y) : 0.f;
    float n3 = (p + 3 < end) ? __uint_as_float(e3.y) : 0.f;
    ax = fmaf(bf_lo(u0), n0, ax); ay = fmaf(bf_hi(u0), n0, ay);
    ax = fmaf(bf_lo(u1), n1, ax); ay = fmaf(bf_hi(u1), n1, ay);
    ax = fmaf(bf_lo(u2), n2, ax); ay = fmaf(bf_hi(u2), n2, ay);
    ax = fmaf(bf_lo(u3), n3, ax); ay = fmaf(bf_hi(u3), n3, ay);
  }
  float di = dinv[i], sn = di * di;              // self-loop norm
  unsigned u = h_u[(size_t)i * 64 + lane];
  ax = fmaf(bf_lo(u), sn, ax);
  ay = fmaf(bf_hi(u), sn, ay);
  float2 bb = *(const float2*)(b1 + lane * 2);
  float vx = ax + bb.x, vy = ay + bb.y;
  vx = vx > 0.f ? vx : expm1f(vx);               // ELU (alpha=1)
  vy = vy > 0.f ? vy : expm1f(vy);
  act1_u[(size_t)i * 64 + lane] = pack_bf16x2(vx, vy);
}

// ---------------- GEMM2: h2[N,8(pad)] = act1_bf16[N,128] @ W2[128,7] ----------------
__global__ __launch_bounds__(256) void k_gemm2(const unsigned* __restrict__ act1_u,
                                               const float* __restrict__ W2,
                                               float* __restrict__ h2) {
  __shared__ float sA[32][HID + 1];
  __shared__ float sW[HID * NCLS];
  const int tid = threadIdx.x;
  const int r0 = blockIdx.x * 32;
#pragma unroll
  for (int j = 0; j < 8; j++) {
    int idx = tid + j * 256;
    int row = idx >> 6;
    int c = idx & 63;
    unsigned u = act1_u[(size_t)(r0 + row) * 64 + c];
    sA[row][c * 2]     = bf_lo(u);
    sA[row][c * 2 + 1] = bf_hi(u);
  }
#pragma unroll
  for (int j = 0; j < 4; j++) {
    int idx = tid + j * 256;
    if (idx < HID * NCLS) sW[idx] = W2[idx];
  }
  __syncthreads();
  const int r = tid >> 3;
  const int c = tid & 7;
  float acc = 0.0f;
  if (c < NCLS) {
#pragma unroll 8
    for (int k = 0; k < HID; k++) acc = fmaf(sA[r][k], sW[k * NCLS + c], acc);
  }
  h2[(size_t)(r0 + r) * 8 + c] = acc;
}

// ---------------- layer-2 aggregation + bias + log_softmax, 4-way pipelined ----------------
__global__ __launch_bounds__(256) void k_agg2(const float* __restrict__ h2,
    const float* __restrict__ dinv, const int* __restrict__ offs, const int* __restrict__ cnt,
    const uint2* __restrict__ csr, const float* __restrict__ b2, float* __restrict__ out) {
  int tid = threadIdx.x;
  int i = blockIdx.x * 32 + (tid >> 3);   // 8 lanes per node
  int f = tid & 7;                        // f==7 is padding lane
  if (i >= N_NODES) return;
  int start = offs[i], len = cnt[i];
  int end = start + len;
  float acc = 0.0f;
  for (int p = start; p < end; p += 4) {
    uint2 e0 = csr[p];
    uint2 e1 = csr[p + 1];
    uint2 e2 = csr[p + 2];
    uint2 e3 = csr[p + 3];
    float v0 = h2[(size_t)e0.x * 8 + f];
    float v1 = h2[(size_t)e1.x * 8 + f];
    float v2 = h2[(size_t)e2.x * 8 + f];
    float v3 = h2[(size_t)e3.x * 8 + f];
    float n0 = __uint_as_float(e0.y);
    float n1 = (p + 1 < end) ? __uint_as_float(e1.y) : 0.f;
    float n2 = (p + 2 < end) ? __uint_as_float(e2.y) : 0.f;
    float n3 = (p + 3 < end) ? __uint_as_float(e3.y) : 0.f;
    acc = fmaf(v0, n0, acc);
    acc = fmaf(v1, n1, acc);
    acc = fmaf(v2, n2, acc);
    acc = fmaf(v3, n3, acc);
  }
  float di = dinv[i];
  acc = fmaf(h2[(size_t)i * 8 + f], di * di, acc);
  float v = acc + ((f < NCLS) ? b2[f] : 0.0f);
  float vm = (f < NCLS) ? v : -INFINITY;
#pragma unroll
  for (int o = 1; o < 8; o <<= 1) vm = fmaxf(vm, __shfl_xor(vm, o, 8));
  float ex = (f < NCLS) ? expf(v - vm) : 0.0f;
  float s8 = ex;
#pragma unroll
  for (int o = 1; o < 8; o <<= 1) s8 += __shfl_xor(s8, o, 8);
  float lse = logf(s8);
  if (f < NCLS) out[(size_t)i * NCLS + f] = v - vm - lse;
}

// ---------------- launch ----------------
extern "C" void kernel_launch(void* const* d_in, const int* in_sizes, int n_in,
                              void* d_out, int out_size, void* d_ws, size_t ws_size,
                              hipStream_t stream) {
  const float* x  = (const float*)d_in[0];
  const int*   ei = (const int*)d_in[1];
  const float* ew = (const float*)d_in[2];
  const float* W1 = (const float*)d_in[3];
  const float* b1 = (const float*)d_in[4];
  const float* W2 = (const float*)d_in[5];
  const float* b2 = (const float*)d_in[6];
  float* out = (float*)d_out;

  char* w = (char*)d_ws;
  const size_t Npad = ((size_t)N_NODES * 4 + 255) & ~(size_t)255;
  size_t off = 0;
  int*      cnt      = (int*)(w + off);      off += Npad;   // \  zeroed together
  int*      cursor   = (int*)(w + off);      off += Npad;   //  | (contiguous)
  float*    degf     = (float*)(w + off);    off += Npad;   // /
  float*    dinv     = (float*)(w + off);    off += Npad;
  int*      offs     = (int*)(w + off);      off += Npad;
  int*      bsum     = (int*)(w + off);      off += 1024;
  uint2*    csr      = (uint2*)(w + off);    off += ((size_t)(N_EDGES + 8) * 8 + 255) & ~(size_t)255;
  unsigned* w1t_u    = (unsigned*)(w + off); off += (size_t)HID * 256 * 4;
  unsigned short* h_u16 = (unsigned short*)(w + off); off += (size_t)N_NODES * HID * 2;
  unsigned* act1_u   = (unsigned*)(w + off); off += (size_t)N_NODES * 64 * 4;
  float*    h2       = (float*)(w + off);    off += (size_t)N_NODES * 8 * 4;

  hipMemsetAsync(cnt, 0, 3 * Npad, stream);

  k_deg_count<<<N_EDGES / 256, 256, 0, stream>>>(ei, ew, degf, cnt);
  k_w1t<<<HID, 256, 0, stream>>>(W1, w1t_u);
  k_dinv<<<(N_NODES + 255) / 256, 256, 0, stream>>>(degf, dinv, csr + N_EDGES);
  const int nb = (N_NODES + 1023) / 1024;
  k_scan_partial<<<nb, 256, 0, stream>>>(cnt, bsum);
  k_scan_bsum<<<1, 64, 0, stream>>>(bsum, nb);
  k_scan_final<<<nb, 256, 0, stream>>>(cnt, bsum, offs);
  k_fill<<<N_EDGES / 256, 256, 0, stream>>>(ei, ew, dinv, offs, cursor, csr);
  k_gemm1<<<(N_NODES + 127) / 128, 256, 0, stream>>>(x, w1t_u, h_u16);
  k_agg1<<<(N_NODES + 3) / 4, 256, 0, stream>>>((const unsigned*)h_u16, dinv, offs, cnt,
                                                csr, b1, act1_u);
  k_gemm2<<<N_NODES / 32, 256, 0, stream>>>(act1_u, W2, h2);
  k_agg2<<<N_NODES / 32, 256, 0, stream>>>(h2, dinv, offs, cnt, csr, b2, out);
}

// Round 4
// 594.259 us; speedup vs baseline: 1.5072x; 1.1776x over previous
//
#include <hip/hip_runtime.h>
#include <hip/hip_bf16.h>
#include <math.h>

#define N_NODES 100000
#define N_EDGES 1600000
#define IN_F 512
#define HID 128
#define NCLS 7

#define DEG_SHIFT 43
#define DEG_WMASK ((1ull << 43) - 1)
#define DEG_SCALE 4194304.0f          // 2^22
#define DEG_INV_SCALE (1.0f / 4194304.0f)

typedef short short8 __attribute__((ext_vector_type(8)));
typedef float f32x4 __attribute__((ext_vector_type(4)));

__device__ __forceinline__ unsigned pack_bf16x2(float a, float b) {
  unsigned ua = __float_as_uint(a), ub = __float_as_uint(b);
  unsigned ra = (ua + 0x7FFFu + ((ua >> 16) & 1u)) >> 16;     // RNE
  unsigned rb = (ub + 0x7FFFu + ((ub >> 16) & 1u)) >> 16;
  return ra | (rb << 16);
}
__device__ __forceinline__ unsigned short f32_to_bf16(float v) {
  unsigned u = __float_as_uint(v);
  return (unsigned short)((u + 0x7FFFu + ((u >> 16) & 1u)) >> 16);
}
__device__ __forceinline__ float bf_lo(unsigned u) { return __uint_as_float(u << 16); }
__device__ __forceinline__ float bf_hi(unsigned u) { return __uint_as_float(u & 0xFFFF0000u); }

// ---------------- degree + count + rank in ONE u64 atomic per edge ----------------
__global__ void k_deg_count(const int* __restrict__ ei, const float* __restrict__ ew,
                            unsigned long long* __restrict__ packed, int* __restrict__ rank) {
  int e = blockIdx.x * blockDim.x + threadIdx.x;
  if (e >= N_EDGES) return;
  int d = ei[N_EDGES + e];
  unsigned long long fx = (unsigned long long)(ew[e] * DEG_SCALE + 0.5f);
  unsigned long long old = atomicAdd(&packed[d], (1ull << DEG_SHIFT) | fx);
  rank[e] = (int)(old >> DEG_SHIFT);    // this edge's slot within its dst bucket
}

__global__ void k_dinv(const unsigned long long* __restrict__ packed,
                       float* __restrict__ dinv, int* __restrict__ cnt,
                       uint2* __restrict__ csr_pad) {
  int i = blockIdx.x * blockDim.x + threadIdx.x;
  if (i < 8) csr_pad[i] = make_uint2(0u, 0u);   // safe over-read entries (src=0, w=0)
  if (i >= N_NODES) return;
  unsigned long long p = packed[i];
  cnt[i] = (int)(p >> DEG_SHIFT);
  float wsum = (float)(p & DEG_WMASK) * DEG_INV_SCALE;
  dinv[i] = rsqrtf(wsum + 1.0f);        // +1 = self-loop weight
}

// ---------------- W1 [512][128] f32 -> W1bT [128][512] bf16 (transposed) ----------------
__global__ void k_w1t(const float* __restrict__ W1, unsigned* __restrict__ w1t_u) {
  int n = blockIdx.x;        // 0..127
  int t = threadIdx.x;       // 0..255 -> k pair 2t, 2t+1
  float a = W1[(size_t)(2 * t) * HID + n];
  float b = W1[(size_t)(2 * t + 1) * HID + n];
  w1t_u[(size_t)n * 256 + t] = pack_bf16x2(a, b);
}

// ---------------- exclusive prefix scan over cnt[N] -> offs[N] ----------------
__global__ void k_scan_partial(const int* __restrict__ cnt, int* __restrict__ bsum) {
  __shared__ int s[256];
  int t = threadIdx.x;
  int base = blockIdx.x * 1024;
  int v = 0;
#pragma unroll
  for (int q = 0; q < 4; q++) {
    int idx = base + t * 4 + q;
    if (idx < N_NODES) v += cnt[idx];
  }
  s[t] = v;
  __syncthreads();
  for (int o = 128; o > 0; o >>= 1) {
    if (t < o) s[t] += s[t + o];
    __syncthreads();
  }
  if (t == 0) bsum[blockIdx.x] = s[0];
}

__global__ void k_scan_bsum(int* bsum, int nb) {
  if (threadIdx.x == 0 && blockIdx.x == 0) {
    int acc = 0;
    for (int i = 0; i < nb; i++) { int v = bsum[i]; bsum[i] = acc; acc += v; }
  }
}

__global__ void k_scan_final(const int* __restrict__ cnt, const int* __restrict__ bsum,
                             int* __restrict__ offs) {
  __shared__ int s[256];
  int t = threadIdx.x;
  int base = blockIdx.x * 1024;
  int v[4]; int sum = 0;
#pragma unroll
  for (int q = 0; q < 4; q++) {
    int idx = base + t * 4 + q;
    v[q] = (idx < N_NODES) ? cnt[idx] : 0;
    sum += v[q];
  }
  s[t] = sum;
  __syncthreads();
  for (int o = 1; o < 256; o <<= 1) {
    int x = (t >= o) ? s[t - o] : 0;
    __syncthreads();
    s[t] += x;
    __syncthreads();
  }
  int acc = s[t] - sum + bsum[blockIdx.x];
#pragma unroll
  for (int q = 0; q < 4; q++) {
    int idx = base + t * 4 + q;
    if (idx < N_NODES) offs[idx] = acc;
    acc += v[q];
  }
}

// ---------------- CSR fill: NO atomics (rank precomputed); stores (src, raw w) ----------------
__global__ void k_fill(const int* __restrict__ ei, const float* __restrict__ ew,
                       const int* __restrict__ rank, const int* __restrict__ offs,
                       uint2* __restrict__ csr) {
  int e = blockIdx.x * blockDim.x + threadIdx.x;
  if (e >= N_EDGES) return;
  int sidx = ei[e];
  int d = ei[N_EDGES + e];
  int p = offs[d] + rank[e];
  csr[p] = make_uint2((unsigned)sidx, __float_as_uint(ew[e]));   // one 8B scatter
}

// ---------------- GEMM1 (MFMA bf16): h'[N,128] = (bf16(x) @ bf16(W1)) * dinv[row] ----------------
#define G1_LDSROW 20   // dwords per LDS tile row (16 data + 4 pad)
__global__ __launch_bounds__(256) void k_gemm1(const float* __restrict__ x,
                                               const unsigned* __restrict__ w1t_u,
                                               const float* __restrict__ dinv,
                                               unsigned short* __restrict__ h_u16) {
  __shared__ unsigned As[128 * G1_LDSROW];
  __shared__ unsigned Bs[128 * G1_LDSROW];
  const int tid = threadIdx.x;
  const int lane = tid & 63;
  const int w = tid >> 6;
  const int wr = w >> 1, wc = w & 1;
  const int quad = lane >> 4;
  const int l16 = lane & 15;
  const int m0 = blockIdx.x * 128;

  f32x4 acc[4][4];
#pragma unroll
  for (int i = 0; i < 4; i++)
#pragma unroll
    for (int j = 0; j < 4; j++) acc[i][j] = (f32x4){0.f, 0.f, 0.f, 0.f};

  for (int k0 = 0; k0 < IN_F; k0 += 32) {
    __syncthreads();
#pragma unroll
    for (int q = 0; q < 4; q++) {
      int flat = q * 256 + tid;
      int row = flat >> 3;
      int c4 = flat & 7;
      int gr = m0 + row;
      float4 v = make_float4(0.f, 0.f, 0.f, 0.f);
      if (gr < N_NODES) v = *(const float4*)(x + (size_t)gr * IN_F + k0 + c4 * 4);
      unsigned lo = pack_bf16x2(v.x, v.y);
      unsigned hi = pack_bf16x2(v.z, v.w);
      *(uint2*)&As[row * G1_LDSROW + c4 * 2] = make_uint2(lo, hi);
    }
#pragma unroll
    for (int q = 0; q < 2; q++) {
      int flat = q * 256 + tid;
      int row = flat >> 2;
      int c = flat & 3;
      uint4 bv = ((const uint4*)w1t_u)[(size_t)row * 64 + (k0 >> 3) + c];
      *(uint4*)&Bs[row * G1_LDSROW + c * 4] = bv;
    }
    __syncthreads();
    short8 af[4], bf[4];
#pragma unroll
    for (int mi = 0; mi < 4; mi++)
      af[mi] = *(const short8*)&As[(wr * 64 + mi * 16 + l16) * G1_LDSROW + quad * 4];
#pragma unroll
    for (int ni = 0; ni < 4; ni++)
      bf[ni] = *(const short8*)&Bs[(wc * 64 + ni * 16 + l16) * G1_LDSROW + quad * 4];
#pragma unroll
    for (int mi = 0; mi < 4; mi++)
#pragma unroll
      for (int ni = 0; ni < 4; ni++)
        acc[mi][ni] = __builtin_amdgcn_mfma_f32_16x16x32_bf16(af[mi], bf[ni], acc[mi][ni], 0, 0, 0);
  }
  // epilogue: scale row by dinv[row] (folds dinv[src] out of the CSR), store bf16
#pragma unroll
  for (int mi = 0; mi < 4; mi++) {
    float df[4];
#pragma unroll
    for (int r = 0; r < 4; r++) {
      int grow = m0 + wr * 64 + mi * 16 + quad * 4 + r;
      df[r] = (grow < N_NODES) ? dinv[grow] : 0.f;
    }
#pragma unroll
    for (int ni = 0; ni < 4; ni++) {
      int gcol = wc * 64 + ni * 16 + l16;
#pragma unroll
      for (int r = 0; r < 4; r++) {
        int grow = m0 + wr * 64 + mi * 16 + quad * 4 + r;
        if (grow < N_NODES)
          h_u16[(size_t)grow * HID + gcol] = f32_to_bf16(acc[mi][ni][r] * df[r]);
      }
    }
  }
}

// ---------------- layer-1 aggregation: wave/node, 8-way pipelined gathers ----------------
// h' rows already carry dinv[src]; out = dinv[i]*(Σ h'[src]*w + h'[i]) + b1, then ELU.
__global__ __launch_bounds__(256) void k_agg1(const unsigned* __restrict__ h_u,
    const float* __restrict__ dinv, const int* __restrict__ offs, const int* __restrict__ cnt,
    const uint2* __restrict__ csr, const float* __restrict__ b1,
    unsigned* __restrict__ act1_u) {
  int i = blockIdx.x * 4 + (threadIdx.x >> 6);   // wave -> node
  int lane = threadIdx.x & 63;                   // lane covers feats [2l, 2l+1]
  if (i >= N_NODES) return;
  int start = offs[i], len = cnt[i];
  int end = start + len;
  float ax = 0.f, ay = 0.f;
  for (int p = start; p < end; p += 8) {
    uint2 e[8];
#pragma unroll
    for (int k = 0; k < 8; k++) e[k] = csr[p + k];   // padded: safe over-read
    unsigned u[8];
#pragma unroll
    for (int k = 0; k < 8; k++) u[k] = h_u[(size_t)e[k].x * 64 + lane];
#pragma unroll
    for (int k = 0; k < 8; k++) {
      float n = (k == 0 || p + k < end) ? __uint_as_float(e[k].y) : 0.f;
      ax = fmaf(bf_lo(u[k]), n, ax);
      ay = fmaf(bf_hi(u[k]), n, ay);
    }
  }
  float di = dinv[i];
  unsigned u = h_u[(size_t)i * 64 + lane];         // self (already * dinv[i])
  float2 bb = *(const float2*)(b1 + lane * 2);
  float vx = fmaf(di, ax + bf_lo(u), bb.x);
  float vy = fmaf(di, ay + bf_hi(u), bb.y);
  vx = vx > 0.f ? vx : expm1f(vx);                 // ELU (alpha=1)
  vy = vy > 0.f ? vy : expm1f(vy);
  act1_u[(size_t)i * 64 + lane] = pack_bf16x2(vx, vy);
}

// ---------------- GEMM2: h2'[N,8] = (act1_bf16[N,128] @ W2[128,7]) * dinv[row] ----------------
__global__ __launch_bounds__(256) void k_gemm2(const unsigned* __restrict__ act1_u,
                                               const float* __restrict__ W2,
                                               const float* __restrict__ dinv,
                                               float* __restrict__ h2) {
  __shared__ float sA[32][HID + 1];
  __shared__ float sW[HID * NCLS];
  const int tid = threadIdx.x;
  const int r0 = blockIdx.x * 32;
#pragma unroll
  for (int j = 0; j < 8; j++) {
    int idx = tid + j * 256;
    int row = idx >> 6;
    int c = idx & 63;
    unsigned u = act1_u[(size_t)(r0 + row) * 64 + c];
    sA[row][c * 2]     = bf_lo(u);
    sA[row][c * 2 + 1] = bf_hi(u);
  }
#pragma unroll
  for (int j = 0; j < 4; j++) {
    int idx = tid + j * 256;
    if (idx < HID * NCLS) sW[idx] = W2[idx];
  }
  __syncthreads();
  const int r = tid >> 3;
  const int c = tid & 7;
  float acc = 0.0f;
  if (c < NCLS) {
#pragma unroll 8
    for (int k = 0; k < HID; k++) acc = fmaf(sA[r][k], sW[k * NCLS + c], acc);
  }
  h2[(size_t)(r0 + r) * 8 + c] = acc * dinv[r0 + r];
}

// ---------------- layer-2 aggregation + bias + log_softmax, 4-way pipelined ----------------
__global__ __launch_bounds__(256) void k_agg2(const float* __restrict__ h2,
    const float* __restrict__ dinv, const int* __restrict__ offs, const int* __restrict__ cnt,
    const uint2* __restrict__ csr, const float* __restrict__ b2, float* __restrict__ out) {
  int tid = threadIdx.x;
  int i = blockIdx.x * 32 + (tid >> 3);   // 8 lanes per node
  int f = tid & 7;                        // f==7 is padding lane
  if (i >= N_NODES) return;
  int start = offs[i], len = cnt[i];
  int end = start + len;
  float acc = 0.0f;
  for (int p = start; p < end; p += 4) {
    uint2 e0 = csr[p];
    uint2 e1 = csr[p + 1];
    uint2 e2 = csr[p + 2];
    uint2 e3 = csr[p + 3];
    float v0 = h2[(size_t)e0.x * 8 + f];
    float v1 = h2[(size_t)e1.x * 8 + f];
    float v2 = h2[(size_t)e2.x * 8 + f];
    float v3 = h2[(size_t)e3.x * 8 + f];
    float n0 = __uint_as_float(e0.y);
    float n1 = (p + 1 < end) ? __uint_as_float(e1.y) : 0.f;
    float n2 = (p + 2 < end) ? __uint_as_float(e2.y) : 0.f;
    float n3 = (p + 3 < end) ? __uint_as_float(e3.y) : 0.f;
    acc = fmaf(v0, n0, acc);
    acc = fmaf(v1, n1, acc);
    acc = fmaf(v2, n2, acc);
    acc = fmaf(v3, n3, acc);
  }
  float di = dinv[i];
  float v = fmaf(di, acc + h2[(size_t)i * 8 + f], (f < NCLS) ? b2[f] : 0.0f);
  float vm = (f < NCLS) ? v : -INFINITY;
#pragma unroll
  for (int o = 1; o < 8; o <<= 1) vm = fmaxf(vm, __shfl_xor(vm, o, 8));
  float ex = (f < NCLS) ? expf(v - vm) : 0.0f;
  float s8 = ex;
#pragma unroll
  for (int o = 1; o < 8; o <<= 1) s8 += __shfl_xor(s8, o, 8);
  float lse = logf(s8);
  if (f < NCLS) out[(size_t)i * NCLS + f] = v - vm - lse;
}

// ---------------- launch ----------------
extern "C" void kernel_launch(void* const* d_in, const int* in_sizes, int n_in,
                              void* d_out, int out_size, void* d_ws, size_t ws_size,
                              hipStream_t stream) {
  const float* x  = (const float*)d_in[0];
  const int*   ei = (const int*)d_in[1];
  const float* ew = (const float*)d_in[2];
  const float* W1 = (const float*)d_in[3];
  const float* b1 = (const float*)d_in[4];
  const float* W2 = (const float*)d_in[5];
  const float* b2 = (const float*)d_in[6];
  float* out = (float*)d_out;

  char* w = (char*)d_ws;
  const size_t Npad  = ((size_t)N_NODES * 4 + 255) & ~(size_t)255;
  const size_t Npad8 = ((size_t)N_NODES * 8 + 255) & ~(size_t)255;
  const size_t Epad  = ((size_t)N_EDGES * 4 + 255) & ~(size_t)255;
  size_t off = 0;
  unsigned long long* packed = (unsigned long long*)(w + off); off += Npad8;  // zeroed
  float*    dinv     = (float*)(w + off);    off += Npad;
  int*      cnt      = (int*)(w + off);      off += Npad;
  int*      offs     = (int*)(w + off);      off += Npad;
  int*      bsum     = (int*)(w + off);      off += 1024;
  int*      rank     = (int*)(w + off);      off += Epad;
  uint2*    csr      = (uint2*)(w + off);    off += ((size_t)(N_EDGES + 8) * 8 + 255) & ~(size_t)255;
  unsigned* w1t_u    = (unsigned*)(w + off); off += (size_t)HID * 256 * 4;
  unsigned short* h_u16 = (unsigned short*)(w + off); off += (size_t)N_NODES * HID * 2;
  unsigned* act1_u   = (unsigned*)(w + off); off += (size_t)N_NODES * 64 * 4;
  float*    h2       = (float*)(w + off);    off += (size_t)N_NODES * 8 * 4;

  hipMemsetAsync(packed, 0, Npad8, stream);

  k_deg_count<<<N_EDGES / 256, 256, 0, stream>>>(ei, ew, packed, rank);
  k_w1t<<<HID, 256, 0, stream>>>(W1, w1t_u);
  k_dinv<<<(N_NODES + 255) / 256, 256, 0, stream>>>(packed, dinv, cnt, csr + N_EDGES);
  const int nb = (N_NODES + 1023) / 1024;
  k_scan_partial<<<nb, 256, 0, stream>>>(cnt, bsum);
  k_scan_bsum<<<1, 64, 0, stream>>>(bsum, nb);
  k_scan_final<<<nb, 256, 0, stream>>>(cnt, bsum, offs);
  k_fill<<<N_EDGES / 256, 256, 0, stream>>>(ei, ew, rank, offs, csr);
  k_gemm1<<<(N_NODES + 127) / 128, 256, 0, stream>>>(x, w1t_u, dinv, h_u16);
  k_agg1<<<(N_NODES + 3) / 4, 256, 0, stream>>>((const unsigned*)h_u16, dinv, offs, cnt,
                                                csr, b1, act1_u);
  k_gemm2<<<N_NODES / 32, 256, 0, stream>>>(act1_u, W2, dinv, h2);
  k_agg2<<<N_NODES / 32, 256, 0, stream>>>(h2, dinv, offs, cnt, csr, b2, out);
}

// Round 5
// 570.031 us; speedup vs baseline: 1.5712x; 1.0425x over previous
//
#include <hip/hip_runtime.h>
#include <hip/hip_bf16.h>
#include <math.h>

#define N_NODES 100000
#define N_EDGES 1600000
#define IN_F 512
#define HID 128
#define NCLS 7

#define DEG_SHIFT 43
#define DEG_WMASK ((1ull << 43) - 1)
#define DEG_SCALE 4194304.0f          // 2^22
#define DEG_INV_SCALE (1.0f / 4194304.0f)

typedef short short8 __attribute__((ext_vector_type(8)));
typedef float f32x4 __attribute__((ext_vector_type(4)));

__device__ __forceinline__ unsigned pack_bf16x2(float a, float b) {
  unsigned ua = __float_as_uint(a), ub = __float_as_uint(b);
  unsigned ra = (ua + 0x7FFFu + ((ua >> 16) & 1u)) >> 16;     // RNE
  unsigned rb = (ub + 0x7FFFu + ((ub >> 16) & 1u)) >> 16;
  return ra | (rb << 16);
}
__device__ __forceinline__ unsigned short f32_to_bf16(float v) {
  unsigned u = __float_as_uint(v);
  return (unsigned short)((u + 0x7FFFu + ((u >> 16) & 1u)) >> 16);
}
__device__ __forceinline__ float bf_lo(unsigned u) { return __uint_as_float(u << 16); }
__device__ __forceinline__ float bf_hi(unsigned u) { return __uint_as_float(u & 0xFFFF0000u); }

// ---------------- degree + count + rank in ONE u64 atomic per edge ----------------
__global__ void k_deg_count(const int* __restrict__ ei, const float* __restrict__ ew,
                            unsigned long long* __restrict__ packed, int* __restrict__ rank) {
  int e = blockIdx.x * blockDim.x + threadIdx.x;
  if (e >= N_EDGES) return;
  int d = ei[N_EDGES + e];
  unsigned long long fx = (unsigned long long)(ew[e] * DEG_SCALE + 0.5f);
  unsigned long long old = atomicAdd(&packed[d], (1ull << DEG_SHIFT) | fx);
  rank[e] = (int)(old >> DEG_SHIFT);    // this edge's slot within its dst bucket
}

__global__ void k_dinv(const unsigned long long* __restrict__ packed,
                       float* __restrict__ dinv, int* __restrict__ cnt,
                       uint2* __restrict__ csr_pad) {
  int i = blockIdx.x * blockDim.x + threadIdx.x;
  if (i < 8) csr_pad[i] = make_uint2(0u, 0u);   // safe over-read entries (src=0, w=0)
  if (i >= N_NODES) return;
  unsigned long long p = packed[i];
  cnt[i] = (int)(p >> DEG_SHIFT);
  float wsum = (float)(p & DEG_WMASK) * DEG_INV_SCALE;
  dinv[i] = rsqrtf(wsum + 1.0f);        // +1 = self-loop weight
}

// ---------------- W1 [512][128] f32 -> W1bT [128][512] bf16 (transposed) ----------------
__global__ void k_w1t(const float* __restrict__ W1, unsigned* __restrict__ w1t_u) {
  int n = blockIdx.x;        // 0..127
  int t = threadIdx.x;       // 0..255 -> k pair 2t, 2t+1
  float a = W1[(size_t)(2 * t) * HID + n];
  float b = W1[(size_t)(2 * t + 1) * HID + n];
  w1t_u[(size_t)n * 256 + t] = pack_bf16x2(a, b);
}

// ---------------- exclusive prefix scan over cnt[N] -> offs[N] ----------------
__global__ void k_scan_partial(const int* __restrict__ cnt, int* __restrict__ bsum) {
  __shared__ int s[256];
  int t = threadIdx.x;
  int base = blockIdx.x * 1024;
  int v = 0;
#pragma unroll
  for (int q = 0; q < 4; q++) {
    int idx = base + t * 4 + q;
    if (idx < N_NODES) v += cnt[idx];
  }
  s[t] = v;
  __syncthreads();
  for (int o = 128; o > 0; o >>= 1) {
    if (t < o) s[t] += s[t + o];
    __syncthreads();
  }
  if (t == 0) bsum[blockIdx.x] = s[0];
}

__global__ void k_scan_bsum(int* bsum, int nb) {
  if (threadIdx.x == 0 && blockIdx.x == 0) {
    int acc = 0;
    for (int i = 0; i < nb; i++) { int v = bsum[i]; bsum[i] = acc; acc += v; }
  }
}

__global__ void k_scan_final(const int* __restrict__ cnt, const int* __restrict__ bsum,
                             int* __restrict__ offs) {
  __shared__ int s[256];
  int t = threadIdx.x;
  int base = blockIdx.x * 1024;
  int v[4]; int sum = 0;
#pragma unroll
  for (int q = 0; q < 4; q++) {
    int idx = base + t * 4 + q;
    v[q] = (idx < N_NODES) ? cnt[idx] : 0;
    sum += v[q];
  }
  s[t] = sum;
  __syncthreads();
  for (int o = 1; o < 256; o <<= 1) {
    int x = (t >= o) ? s[t - o] : 0;
    __syncthreads();
    s[t] += x;
    __syncthreads();
  }
  int acc = s[t] - sum + bsum[blockIdx.x];
#pragma unroll
  for (int q = 0; q < 4; q++) {
    int idx = base + t * 4 + q;
    if (idx < N_NODES) offs[idx] = acc;
    acc += v[q];
  }
}

// ---------------- CSR fill: NO atomics (rank precomputed); stores (src, raw w) ----------------
__global__ void k_fill(const int* __restrict__ ei, const float* __restrict__ ew,
                       const int* __restrict__ rank, const int* __restrict__ offs,
                       uint2* __restrict__ csr) {
  int e = blockIdx.x * blockDim.x + threadIdx.x;
  if (e >= N_EDGES) return;
  int sidx = ei[e];
  int d = ei[N_EDGES + e];
  int p = offs[d] + rank[e];
  csr[p] = make_uint2((unsigned)sidx, __float_as_uint(ew[e]));   // one 8B scatter
}

// ---------------- GEMM1 (MFMA bf16, BARRIER-FREE): h'[N,128] = (x @ W1)*dinv[row] ----------------
// A streamed global->VGPR->bf16 frag (A[m=l16][k=quad*8+j] = 2 dwordx4/lane, coalesced).
// B frags read directly from w1t_u (L1/L2-hot 128 KB, 16 contiguous B per frag).
// No LDS, no __syncthreads, software-pipelined one k-step ahead -> pure HBM streaming.
__global__ __launch_bounds__(256) void k_gemm1(const float* __restrict__ x,
                                               const unsigned* __restrict__ w1t_u,
                                               const float* __restrict__ dinv,
                                               unsigned short* __restrict__ h_u16) {
  const int tid = threadIdx.x;
  const int lane = tid & 63;
  const int w = tid >> 6;
  const int wr = w >> 1, wc = w & 1;
  const int quad = lane >> 4;
  const int l16 = lane & 15;
  const int m0 = blockIdx.x * 128;

  const float* arow[4];
#pragma unroll
  for (int mi = 0; mi < 4; mi++) {
    int gr = m0 + wr * 64 + mi * 16 + l16;
    if (gr > N_NODES - 1) gr = N_NODES - 1;   // clamp; results for OOB rows discarded
    arow[mi] = x + (size_t)gr * IN_F + quad * 8;
  }
  const unsigned* brow[4];
#pragma unroll
  for (int ni = 0; ni < 4; ni++) {
    int n = wc * 64 + ni * 16 + l16;
    brow[ni] = w1t_u + (size_t)n * 256 + quad * 4;
  }

  f32x4 acc[4][4];
#pragma unroll
  for (int i = 0; i < 4; i++)
#pragma unroll
    for (int j = 0; j < 4; j++) acc[i][j] = (f32x4){0.f, 0.f, 0.f, 0.f};

  float4 a_cur[4][2];
  uint4 b_cur[4];
#pragma unroll
  for (int mi = 0; mi < 4; mi++) {
    a_cur[mi][0] = *(const float4*)(arow[mi]);
    a_cur[mi][1] = *(const float4*)(arow[mi] + 4);
  }
#pragma unroll
  for (int ni = 0; ni < 4; ni++) b_cur[ni] = *(const uint4*)(brow[ni]);

  for (int step = 0; step < 15; step++) {
    // prefetch step+1 (12 independent dwordx4 in flight over this step's compute)
    float4 a_nxt[4][2];
    uint4 b_nxt[4];
    const int ko = (step + 1) * 32;   // f32 offset
    const int kd = (step + 1) * 16;   // dword offset
#pragma unroll
    for (int mi = 0; mi < 4; mi++) {
      a_nxt[mi][0] = *(const float4*)(arow[mi] + ko);
      a_nxt[mi][1] = *(const float4*)(arow[mi] + ko + 4);
    }
#pragma unroll
    for (int ni = 0; ni < 4; ni++) b_nxt[ni] = *(const uint4*)(brow[ni] + kd);
    // compute current step
    short8 af[4];
#pragma unroll
    for (int mi = 0; mi < 4; mi++) {
      union { short8 s; unsigned u[4]; } t;
      t.u[0] = pack_bf16x2(a_cur[mi][0].x, a_cur[mi][0].y);
      t.u[1] = pack_bf16x2(a_cur[mi][0].z, a_cur[mi][0].w);
      t.u[2] = pack_bf16x2(a_cur[mi][1].x, a_cur[mi][1].y);
      t.u[3] = pack_bf16x2(a_cur[mi][1].z, a_cur[mi][1].w);
      af[mi] = t.s;
    }
#pragma unroll
    for (int mi = 0; mi < 4; mi++)
#pragma unroll
      for (int ni = 0; ni < 4; ni++)
        acc[mi][ni] = __builtin_amdgcn_mfma_f32_16x16x32_bf16(
            af[mi], *(const short8*)&b_cur[ni], acc[mi][ni], 0, 0, 0);
    // rotate
#pragma unroll
    for (int mi = 0; mi < 4; mi++) { a_cur[mi][0] = a_nxt[mi][0]; a_cur[mi][1] = a_nxt[mi][1]; }
#pragma unroll
    for (int ni = 0; ni < 4; ni++) b_cur[ni] = b_nxt[ni];
  }
  {  // final step (no prefetch)
    short8 af[4];
#pragma unroll
    for (int mi = 0; mi < 4; mi++) {
      union { short8 s; unsigned u[4]; } t;
      t.u[0] = pack_bf16x2(a_cur[mi][0].x, a_cur[mi][0].y);
      t.u[1] = pack_bf16x2(a_cur[mi][0].z, a_cur[mi][0].w);
      t.u[2] = pack_bf16x2(a_cur[mi][1].x, a_cur[mi][1].y);
      t.u[3] = pack_bf16x2(a_cur[mi][1].z, a_cur[mi][1].w);
      af[mi] = t.s;
    }
#pragma unroll
    for (int mi = 0; mi < 4; mi++)
#pragma unroll
      for (int ni = 0; ni < 4; ni++)
        acc[mi][ni] = __builtin_amdgcn_mfma_f32_16x16x32_bf16(
            af[mi], *(const short8*)&b_cur[ni], acc[mi][ni], 0, 0, 0);
  }
  // epilogue: scale row by dinv[row] (folds dinv[src] out of the CSR), store bf16
#pragma unroll
  for (int mi = 0; mi < 4; mi++) {
    float df[4];
#pragma unroll
    for (int r = 0; r < 4; r++) {
      int grow = m0 + wr * 64 + mi * 16 + quad * 4 + r;
      df[r] = (grow < N_NODES) ? dinv[grow] : 0.f;
    }
#pragma unroll
    for (int ni = 0; ni < 4; ni++) {
      int gcol = wc * 64 + ni * 16 + l16;
#pragma unroll
      for (int r = 0; r < 4; r++) {
        int grow = m0 + wr * 64 + mi * 16 + quad * 4 + r;
        if (grow < N_NODES)
          h_u16[(size_t)grow * HID + gcol] = f32_to_bf16(acc[mi][ni][r] * df[r]);
      }
    }
  }
}

// ---------------- layer-1 aggregation: wave/node, 8-way pipelined gathers ----------------
// h' rows already carry dinv[src]; out = dinv[i]*(Σ h'[src]*w + h'[i]) + b1, then ELU.
__global__ __launch_bounds__(256) void k_agg1(const unsigned* __restrict__ h_u,
    const float* __restrict__ dinv, const int* __restrict__ offs, const int* __restrict__ cnt,
    const uint2* __restrict__ csr, const float* __restrict__ b1,
    unsigned* __restrict__ act1_u) {
  int i = blockIdx.x * 4 + (threadIdx.x >> 6);   // wave -> node
  int lane = threadIdx.x & 63;                   // lane covers feats [2l, 2l+1]
  if (i >= N_NODES) return;
  int start = offs[i], len = cnt[i];
  int end = start + len;
  float ax = 0.f, ay = 0.f;
  for (int p = start; p < end; p += 8) {
    uint2 e[8];
#pragma unroll
    for (int k = 0; k < 8; k++) e[k] = csr[p + k];   // padded: safe over-read
    unsigned u[8];
#pragma unroll
    for (int k = 0; k < 8; k++) u[k] = h_u[(size_t)e[k].x * 64 + lane];
#pragma unroll
    for (int k = 0; k < 8; k++) {
      float n = (k == 0 || p + k < end) ? __uint_as_float(e[k].y) : 0.f;
      ax = fmaf(bf_lo(u[k]), n, ax);
      ay = fmaf(bf_hi(u[k]), n, ay);
    }
  }
  float di = dinv[i];
  unsigned u = h_u[(size_t)i * 64 + lane];         // self (already * dinv[i])
  float2 bb = *(const float2*)(b1 + lane * 2);
  float vx = fmaf(di, ax + bf_lo(u), bb.x);
  float vy = fmaf(di, ay + bf_hi(u), bb.y);
  vx = vx > 0.f ? vx : expm1f(vx);                 // ELU (alpha=1)
  vy = vy > 0.f ? vy : expm1f(vy);
  act1_u[(size_t)i * 64 + lane] = pack_bf16x2(vx, vy);
}

// ---------------- GEMM2: h2'[N,8] = (act1_bf16[N,128] @ W2[128,7]) * dinv[row] ----------------
__global__ __launch_bounds__(256) void k_gemm2(const unsigned* __restrict__ act1_u,
                                               const float* __restrict__ W2,
                                               const float* __restrict__ dinv,
                                               float* __restrict__ h2) {
  __shared__ float sA[32][HID + 1];
  __shared__ float sW[HID * NCLS];
  const int tid = threadIdx.x;
  const int r0 = blockIdx.x * 32;
#pragma unroll
  for (int j = 0; j < 8; j++) {
    int idx = tid + j * 256;
    int row = idx >> 6;
    int c = idx & 63;
    unsigned u = act1_u[(size_t)(r0 + row) * 64 + c];
    sA[row][c * 2]     = bf_lo(u);
    sA[row][c * 2 + 1] = bf_hi(u);
  }
#pragma unroll
  for (int j = 0; j < 4; j++) {
    int idx = tid + j * 256;
    if (idx < HID * NCLS) sW[idx] = W2[idx];
  }
  __syncthreads();
  const int r = tid >> 3;
  const int c = tid & 7;
  float acc = 0.0f;
  if (c < NCLS) {
#pragma unroll 8
    for (int k = 0; k < HID; k++) acc = fmaf(sA[r][k], sW[k * NCLS + c], acc);
  }
  h2[(size_t)(r0 + r) * 8 + c] = acc * dinv[r0 + r];
}

// ---------------- layer-2 aggregation + bias + log_softmax, 4-way pipelined ----------------
__global__ __launch_bounds__(256) void k_agg2(const float* __restrict__ h2,
    const float* __restrict__ dinv, const int* __restrict__ offs, const int* __restrict__ cnt,
    const uint2* __restrict__ csr, const float* __restrict__ b2, float* __restrict__ out) {
  int tid = threadIdx.x;
  int i = blockIdx.x * 32 + (tid >> 3);   // 8 lanes per node
  int f = tid & 7;                        // f==7 is padding lane
  if (i >= N_NODES) return;
  int start = offs[i], len = cnt[i];
  int end = start + len;
  float acc = 0.0f;
  for (int p = start; p < end; p += 4) {
    uint2 e0 = csr[p];
    uint2 e1 = csr[p + 1];
    uint2 e2 = csr[p + 2];
    uint2 e3 = csr[p + 3];
    float v0 = h2[(size_t)e0.x * 8 + f];
    float v1 = h2[(size_t)e1.x * 8 + f];
    float v2 = h2[(size_t)e2.x * 8 + f];
    float v3 = h2[(size_t)e3.x * 8 + f];
    float n0 = __uint_as_float(e0.y);
    float n1 = (p + 1 < end) ? __uint_as_float(e1.y) : 0.f;
    float n2 = (p + 2 < end) ? __uint_as_float(e2.y) : 0.f;
    float n3 = (p + 3 < end) ? __uint_as_float(e3.y) : 0.f;
    acc = fmaf(v0, n0, acc);
    acc = fmaf(v1, n1, acc);
    acc = fmaf(v2, n2, acc);
    acc = fmaf(v3, n3, acc);
  }
  float di = dinv[i];
  float v = fmaf(di, acc + h2[(size_t)i * 8 + f], (f < NCLS) ? b2[f] : 0.0f);
  float vm = (f < NCLS) ? v : -INFINITY;
#pragma unroll
  for (int o = 1; o < 8; o <<= 1) vm = fmaxf(vm, __shfl_xor(vm, o, 8));
  float ex = (f < NCLS) ? expf(v - vm) : 0.0f;
  float s8 = ex;
#pragma unroll
  for (int o = 1; o < 8; o <<= 1) s8 += __shfl_xor(s8, o, 8);
  float lse = logf(s8);
  if (f < NCLS) out[(size_t)i * NCLS + f] = v - vm - lse;
}

// ---------------- launch ----------------
extern "C" void kernel_launch(void* const* d_in, const int* in_sizes, int n_in,
                              void* d_out, int out_size, void* d_ws, size_t ws_size,
                              hipStream_t stream) {
  const float* x  = (const float*)d_in[0];
  const int*   ei = (const int*)d_in[1];
  const float* ew = (const float*)d_in[2];
  const float* W1 = (const float*)d_in[3];
  const float* b1 = (const float*)d_in[4];
  const float* W2 = (const float*)d_in[5];
  const float* b2 = (const float*)d_in[6];
  float* out = (float*)d_out;

  char* w = (char*)d_ws;
  const size_t Npad  = ((size_t)N_NODES * 4 + 255) & ~(size_t)255;
  const size_t Npad8 = ((size_t)N_NODES * 8 + 255) & ~(size_t)255;
  const size_t Epad  = ((size_t)N_EDGES * 4 + 255) & ~(size_t)255;
  size_t off = 0;
  unsigned long long* packed = (unsigned long long*)(w + off); off += Npad8;  // zeroed
  float*    dinv     = (float*)(w + off);    off += Npad;
  int*      cnt      = (int*)(w + off);      off += Npad;
  int*      offs     = (int*)(w + off);      off += Npad;
  int*      bsum     = (int*)(w + off);      off += 1024;
  int*      rank     = (int*)(w + off);      off += Epad;
  uint2*    csr      = (uint2*)(w + off);    off += ((size_t)(N_EDGES + 8) * 8 + 255) & ~(size_t)255;
  unsigned* w1t_u    = (unsigned*)(w + off); off += (size_t)HID * 256 * 4;
  unsigned short* h_u16 = (unsigned short*)(w + off); off += (size_t)N_NODES * HID * 2;
  unsigned* act1_u   = (unsigned*)(w + off); off += (size_t)N_NODES * 64 * 4;
  float*    h2       = (float*)(w + off);    off += (size_t)N_NODES * 8 * 4;

  hipMemsetAsync(packed, 0, Npad8, stream);

  k_deg_count<<<N_EDGES / 256, 256, 0, stream>>>(ei, ew, packed, rank);
  k_w1t<<<HID, 256, 0, stream>>>(W1, w1t_u);
  k_dinv<<<(N_NODES + 255) / 256, 256, 0, stream>>>(packed, dinv, cnt, csr + N_EDGES);
  const int nb = (N_NODES + 1023) / 1024;
  k_scan_partial<<<nb, 256, 0, stream>>>(cnt, bsum);
  k_scan_bsum<<<1, 64, 0, stream>>>(bsum, nb);
  k_scan_final<<<nb, 256, 0, stream>>>(cnt, bsum, offs);
  k_fill<<<N_EDGES / 256, 256, 0, stream>>>(ei, ew, rank, offs, csr);
  k_gemm1<<<(N_NODES + 127) / 128, 256, 0, stream>>>(x, w1t_u, dinv, h_u16);
  k_agg1<<<(N_NODES + 3) / 4, 256, 0, stream>>>((const unsigned*)h_u16, dinv, offs, cnt,
                                                csr, b1, act1_u);
  k_gemm2<<<N_NODES / 32, 256, 0, stream>>>(act1_u, W2, dinv, h2);
  k_agg2<<<N_NODES / 32, 256, 0, stream>>>(h2, dinv, offs, cnt, csr, b2, out);
}

// Round 6
// 549.233 us; speedup vs baseline: 1.6307x; 1.0379x over previous
//
#include <hip/hip_runtime.h>
#include <hip/hip_bf16.h>
#include <math.h>

#define N_NODES 100000
#define N_EDGES 1600000
#define IN_F 512
#define HID 128
#define NCLS 7

#define DEG_SHIFT 43
#define DEG_WMASK ((1ull << 43) - 1)
#define DEG_SCALE 4194304.0f          // 2^22
#define DEG_INV_SCALE (1.0f / 4194304.0f)

typedef short short8 __attribute__((ext_vector_type(8)));
typedef float f32x4 __attribute__((ext_vector_type(4)));

__device__ __forceinline__ unsigned pack_bf16x2(float a, float b) {
  unsigned ua = __float_as_uint(a), ub = __float_as_uint(b);
  unsigned ra = (ua + 0x7FFFu + ((ua >> 16) & 1u)) >> 16;     // RNE
  unsigned rb = (ub + 0x7FFFu + ((ub >> 16) & 1u)) >> 16;
  return ra | (rb << 16);
}
__device__ __forceinline__ unsigned short f32_to_bf16(float v) {
  unsigned u = __float_as_uint(v);
  return (unsigned short)((u + 0x7FFFu + ((u >> 16) & 1u)) >> 16);
}
__device__ __forceinline__ float bf_lo(unsigned u) { return __uint_as_float(u << 16); }
__device__ __forceinline__ float bf_hi(unsigned u) { return __uint_as_float(u & 0xFFFF0000u); }

// ---------------- degree + count + rank in ONE u64 atomic per edge ----------------
__global__ void k_deg_count(const int* __restrict__ ei, const float* __restrict__ ew,
                            unsigned long long* __restrict__ packed, int* __restrict__ rank) {
  int e = blockIdx.x * blockDim.x + threadIdx.x;
  if (e >= N_EDGES) return;
  int d = ei[N_EDGES + e];
  unsigned long long fx = (unsigned long long)(ew[e] * DEG_SCALE + 0.5f);
  unsigned long long old = atomicAdd(&packed[d], (1ull << DEG_SHIFT) | fx);
  rank[e] = (int)(old >> DEG_SHIFT);    // this edge's slot within its dst bucket
}

__global__ void k_dinv(const unsigned long long* __restrict__ packed,
                       float* __restrict__ dinv, int* __restrict__ cnt,
                       uint2* __restrict__ csr_pad) {
  int i = blockIdx.x * blockDim.x + threadIdx.x;
  if (i < 8) csr_pad[i] = make_uint2(0u, 0u);   // safe over-read entries (src=0, w=0)
  if (i >= N_NODES) return;
  unsigned long long p = packed[i];
  cnt[i] = (int)(p >> DEG_SHIFT);
  float wsum = (float)(p & DEG_WMASK) * DEG_INV_SCALE;
  dinv[i] = rsqrtf(wsum + 1.0f);        // +1 = self-loop weight
}

// ---------------- W1 [512][128] f32 -> frag-major bf16 layout ----------------
// w1bf[((s*8 + t)*64 + lane)] (uint4): bf16 pairs of W1[k][n] with
// n = t*16 + (lane&15), k = s*32 + (lane>>4)*8 + {0..7}.
// One B fragment (s,t) = 64 lanes x 16B = 1 KB fully contiguous, lane-ordered.
__global__ void k_w1t(const float* __restrict__ W1, uint4* __restrict__ w1bf) {
  int idx = blockIdx.x * 256 + threadIdx.x;   // 0..8191
  int lane = idx & 63;
  int st = idx >> 6;                          // s*8 + t
  int t = st & 7, s = st >> 3;
  int n = t * 16 + (lane & 15);
  int k0 = s * 32 + (lane >> 4) * 8;
  uint4 v;
  v.x = pack_bf16x2(W1[(size_t)(k0 + 0) * HID + n], W1[(size_t)(k0 + 1) * HID + n]);
  v.y = pack_bf16x2(W1[(size_t)(k0 + 2) * HID + n], W1[(size_t)(k0 + 3) * HID + n]);
  v.z = pack_bf16x2(W1[(size_t)(k0 + 4) * HID + n], W1[(size_t)(k0 + 5) * HID + n]);
  v.w = pack_bf16x2(W1[(size_t)(k0 + 6) * HID + n], W1[(size_t)(k0 + 7) * HID + n]);
  w1bf[idx] = v;
}

// ---------------- exclusive prefix scan over cnt[N] -> offs[N] ----------------
__global__ void k_scan_partial(const int* __restrict__ cnt, int* __restrict__ bsum) {
  __shared__ int s[256];
  int t = threadIdx.x;
  int base = blockIdx.x * 1024;
  int v = 0;
#pragma unroll
  for (int q = 0; q < 4; q++) {
    int idx = base + t * 4 + q;
    if (idx < N_NODES) v += cnt[idx];
  }
  s[t] = v;
  __syncthreads();
  for (int o = 128; o > 0; o >>= 1) {
    if (t < o) s[t] += s[t + o];
    __syncthreads();
  }
  if (t == 0) bsum[blockIdx.x] = s[0];
}

__global__ void k_scan_bsum(int* bsum, int nb) {
  if (threadIdx.x == 0 && blockIdx.x == 0) {
    int acc = 0;
    for (int i = 0; i < nb; i++) { int v = bsum[i]; bsum[i] = acc; acc += v; }
  }
}

__global__ void k_scan_final(const int* __restrict__ cnt, const int* __restrict__ bsum,
                             int* __restrict__ offs) {
  __shared__ int s[256];
  int t = threadIdx.x;
  int base = blockIdx.x * 1024;
  int v[4]; int sum = 0;
#pragma unroll
  for (int q = 0; q < 4; q++) {
    int idx = base + t * 4 + q;
    v[q] = (idx < N_NODES) ? cnt[idx] : 0;
    sum += v[q];
  }
  s[t] = sum;
  __syncthreads();
  for (int o = 1; o < 256; o <<= 1) {
    int x = (t >= o) ? s[t - o] : 0;
    __syncthreads();
    s[t] += x;
    __syncthreads();
  }
  int acc = s[t] - sum + bsum[blockIdx.x];
#pragma unroll
  for (int q = 0; q < 4; q++) {
    int idx = base + t * 4 + q;
    if (idx < N_NODES) offs[idx] = acc;
    acc += v[q];
  }
}

// ---------------- CSR fill: NO atomics (rank precomputed); stores (src, raw w) ----------------
__global__ void k_fill(const int* __restrict__ ei, const float* __restrict__ ew,
                       const int* __restrict__ rank, const int* __restrict__ offs,
                       uint2* __restrict__ csr) {
  int e = blockIdx.x * blockDim.x + threadIdx.x;
  if (e >= N_EDGES) return;
  int sidx = ei[e];
  int d = ei[N_EDGES + e];
  int p = offs[d] + rank[e];
  csr[p] = make_uint2((unsigned)sidx, __float_as_uint(ew[e]));   // one 8B scatter
}

// ---------------- GEMM1: wave-synchronous, all-contiguous loads, no barriers ----------------
// Each wave: M=16 rows, N=128, K=512. 6250 waves total (100000/16 exactly).
// A: per K-half, 16 loads of one contiguous 1KB row-half each -> bf16 -> wave-private LDS.
// B: frag-major w1bf, every fragment = one contiguous 1KB load (L2-resident 128KB).
#define SLABSTRIDE 132   // dwords per LDS row (128 data + 4 pad)
__global__ __launch_bounds__(256) void k_gemm1(const float* __restrict__ x,
                                               const uint4* __restrict__ w1bf,
                                               const float* __restrict__ dinv,
                                               unsigned short* __restrict__ h_u16) {
  __shared__ unsigned slab[4 * 16 * SLABSTRIDE];
  const int tid = threadIdx.x;
  const int lane = tid & 63;
  const int wv = tid >> 6;
  const int gw = blockIdx.x * 4 + wv;          // global wave id
  if (gw >= N_NODES / 16) return;
  const int m0 = gw * 16;
  unsigned* ws = slab + wv * 16 * SLABSTRIDE;  // wave-private slab
  const int l16 = lane & 15, quad = lane >> 4;

  f32x4 acc[8];
#pragma unroll
  for (int t = 0; t < 8; t++) acc[t] = (f32x4){0.f, 0.f, 0.f, 0.f};

#pragma unroll
  for (int hf = 0; hf < 2; hf++) {
    // ---- stage: 16 rows x 256 k, each load = 1KB contiguous ----
#pragma unroll
    for (int b = 0; b < 2; b++) {
      float4 v[8];
#pragma unroll
      for (int i = 0; i < 8; i++) {
        int row = b * 8 + i;
        v[i] = *(const float4*)(x + (size_t)(m0 + row) * IN_F + hf * 256 + lane * 4);
      }
#pragma unroll
      for (int i = 0; i < 8; i++) {
        int row = b * 8 + i;
        unsigned lo = pack_bf16x2(v[i].x, v[i].y);
        unsigned hi = pack_bf16x2(v[i].z, v[i].w);
        *(uint2*)&ws[row * SLABSTRIDE + lane * 2] = make_uint2(lo, hi);
      }
    }
    __threadfence_block();   // wave-local: drain own ds_writes before frag reads
    // ---- compute: 8 k-steps, A frag from LDS, B frags contiguous from global ----
#pragma unroll
    for (int ks = 0; ks < 8; ks++) {
      short8 af = *(const short8*)&ws[l16 * SLABSTRIDE + ks * 16 + quad * 4];
      const uint4* bbase = w1bf + (size_t)(hf * 8 + ks) * 8 * 64 + lane;
#pragma unroll
      for (int t = 0; t < 8; t++) {
        uint4 bv = bbase[t * 64];
        acc[t] = __builtin_amdgcn_mfma_f32_16x16x32_bf16(af, *(const short8*)&bv,
                                                         acc[t], 0, 0, 0);
      }
    }
  }
  // ---- epilogue: C/D row = quad*4+r, col = t*16+l16; scale by dinv[row], store bf16 ----
  float df[4];
#pragma unroll
  for (int r = 0; r < 4; r++) df[r] = dinv[m0 + quad * 4 + r];
#pragma unroll
  for (int t = 0; t < 8; t++)
#pragma unroll
    for (int r = 0; r < 4; r++)
      h_u16[(size_t)(m0 + quad * 4 + r) * HID + t * 16 + l16] = f32_to_bf16(acc[t][r] * df[r]);
}

// ---------------- layer-1 aggregation: wave/node, 8-way pipelined gathers ----------------
__global__ __launch_bounds__(256) void k_agg1(const unsigned* __restrict__ h_u,
    const float* __restrict__ dinv, const int* __restrict__ offs, const int* __restrict__ cnt,
    const uint2* __restrict__ csr, const float* __restrict__ b1,
    unsigned* __restrict__ act1_u) {
  int i = blockIdx.x * 4 + (threadIdx.x >> 6);   // wave -> node
  int lane = threadIdx.x & 63;                   // lane covers feats [2l, 2l+1]
  if (i >= N_NODES) return;
  int start = offs[i], len = cnt[i];
  int end = start + len;
  float ax = 0.f, ay = 0.f;
  for (int p = start; p < end; p += 8) {
    uint2 e[8];
#pragma unroll
    for (int k = 0; k < 8; k++) e[k] = csr[p + k];   // padded: safe over-read
    unsigned u[8];
#pragma unroll
    for (int k = 0; k < 8; k++) u[k] = h_u[(size_t)e[k].x * 64 + lane];
#pragma unroll
    for (int k = 0; k < 8; k++) {
      float n = (k == 0 || p + k < end) ? __uint_as_float(e[k].y) : 0.f;
      ax = fmaf(bf_lo(u[k]), n, ax);
      ay = fmaf(bf_hi(u[k]), n, ay);
    }
  }
  float di = dinv[i];
  unsigned u = h_u[(size_t)i * 64 + lane];         // self (already * dinv[i])
  float2 bb = *(const float2*)(b1 + lane * 2);
  float vx = fmaf(di, ax + bf_lo(u), bb.x);
  float vy = fmaf(di, ay + bf_hi(u), bb.y);
  vx = vx > 0.f ? vx : expm1f(vx);                 // ELU (alpha=1)
  vy = vy > 0.f ? vy : expm1f(vy);
  act1_u[(size_t)i * 64 + lane] = pack_bf16x2(vx, vy);
}

// ---------------- GEMM2: h2'[N,8] = (act1_bf16[N,128] @ W2[128,7]) * dinv[row] ----------------
__global__ __launch_bounds__(256) void k_gemm2(const unsigned* __restrict__ act1_u,
                                               const float* __restrict__ W2,
                                               const float* __restrict__ dinv,
                                               float* __restrict__ h2) {
  __shared__ float sA[32][HID + 1];
  __shared__ float sW[HID * NCLS];
  const int tid = threadIdx.x;
  const int r0 = blockIdx.x * 32;
#pragma unroll
  for (int j = 0; j < 8; j++) {
    int idx = tid + j * 256;
    int row = idx >> 6;
    int c = idx & 63;
    unsigned u = act1_u[(size_t)(r0 + row) * 64 + c];
    sA[row][c * 2]     = bf_lo(u);
    sA[row][c * 2 + 1] = bf_hi(u);
  }
#pragma unroll
  for (int j = 0; j < 4; j++) {
    int idx = tid + j * 256;
    if (idx < HID * NCLS) sW[idx] = W2[idx];
  }
  __syncthreads();
  const int r = tid >> 3;
  const int c = tid & 7;
  float acc = 0.0f;
  if (c < NCLS) {
#pragma unroll 8
    for (int k = 0; k < HID; k++) acc = fmaf(sA[r][k], sW[k * NCLS + c], acc);
  }
  h2[(size_t)(r0 + r) * 8 + c] = acc * dinv[r0 + r];
}

// ---------------- layer-2 aggregation + bias + log_softmax, 4-way pipelined ----------------
__global__ __launch_bounds__(256) void k_agg2(const float* __restrict__ h2,
    const float* __restrict__ dinv, const int* __restrict__ offs, const int* __restrict__ cnt,
    const uint2* __restrict__ csr, const float* __restrict__ b2, float* __restrict__ out) {
  int tid = threadIdx.x;
  int i = blockIdx.x * 32 + (tid >> 3);   // 8 lanes per node
  int f = tid & 7;                        // f==7 is padding lane
  if (i >= N_NODES) return;
  int start = offs[i], len = cnt[i];
  int end = start + len;
  float acc = 0.0f;
  for (int p = start; p < end; p += 4) {
    uint2 e0 = csr[p];
    uint2 e1 = csr[p + 1];
    uint2 e2 = csr[p + 2];
    uint2 e3 = csr[p + 3];
    float v0 = h2[(size_t)e0.x * 8 + f];
    float v1 = h2[(size_t)e1.x * 8 + f];
    float v2 = h2[(size_t)e2.x * 8 + f];
    float v3 = h2[(size_t)e3.x * 8 + f];
    float n0 = __uint_as_float(e0.y);
    float n1 = (p + 1 < end) ? __uint_as_float(e1.y) : 0.f;
    float n2 = (p + 2 < end) ? __uint_as_float(e2.y) : 0.f;
    float n3 = (p + 3 < end) ? __uint_as_float(e3.y) : 0.f;
    acc = fmaf(v0, n0, acc);
    acc = fmaf(v1, n1, acc);
    acc = fmaf(v2, n2, acc);
    acc = fmaf(v3, n3, acc);
  }
  float di = dinv[i];
  float v = fmaf(di, acc + h2[(size_t)i * 8 + f], (f < NCLS) ? b2[f] : 0.0f);
  float vm = (f < NCLS) ? v : -INFINITY;
#pragma unroll
  for (int o = 1; o < 8; o <<= 1) vm = fmaxf(vm, __shfl_xor(vm, o, 8));
  float ex = (f < NCLS) ? expf(v - vm) : 0.0f;
  float s8 = ex;
#pragma unroll
  for (int o = 1; o < 8; o <<= 1) s8 += __shfl_xor(s8, o, 8);
  float lse = logf(s8);
  if (f < NCLS) out[(size_t)i * NCLS + f] = v - vm - lse;
}

// ---------------- launch ----------------
extern "C" void kernel_launch(void* const* d_in, const int* in_sizes, int n_in,
                              void* d_out, int out_size, void* d_ws, size_t ws_size,
                              hipStream_t stream) {
  const float* x  = (const float*)d_in[0];
  const int*   ei = (const int*)d_in[1];
  const float* ew = (const float*)d_in[2];
  const float* W1 = (const float*)d_in[3];
  const float* b1 = (const float*)d_in[4];
  const float* W2 = (const float*)d_in[5];
  const float* b2 = (const float*)d_in[6];
  float* out = (float*)d_out;

  char* w = (char*)d_ws;
  const size_t Npad  = ((size_t)N_NODES * 4 + 255) & ~(size_t)255;
  const size_t Npad8 = ((size_t)N_NODES * 8 + 255) & ~(size_t)255;
  const size_t Epad  = ((size_t)N_EDGES * 4 + 255) & ~(size_t)255;
  size_t off = 0;
  unsigned long long* packed = (unsigned long long*)(w + off); off += Npad8;  // zeroed
  float*    dinv     = (float*)(w + off);    off += Npad;
  int*      cnt      = (int*)(w + off);      off += Npad;
  int*      offs     = (int*)(w + off);      off += Npad;
  int*      bsum     = (int*)(w + off);      off += 1024;
  int*      rank     = (int*)(w + off);      off += Epad;
  uint2*    csr      = (uint2*)(w + off);    off += ((size_t)(N_EDGES + 8) * 8 + 255) & ~(size_t)255;
  uint4*    w1bf     = (uint4*)(w + off);    off += (size_t)8192 * 16;        // 128 KB
  unsigned short* h_u16 = (unsigned short*)(w + off); off += (size_t)N_NODES * HID * 2;
  unsigned* act1_u   = (unsigned*)(w + off); off += (size_t)N_NODES * 64 * 4;
  float*    h2       = (float*)(w + off);    off += (size_t)N_NODES * 8 * 4;

  hipMemsetAsync(packed, 0, Npad8, stream);

  k_deg_count<<<N_EDGES / 256, 256, 0, stream>>>(ei, ew, packed, rank);
  k_w1t<<<32, 256, 0, stream>>>(W1, w1bf);
  k_dinv<<<(N_NODES + 255) / 256, 256, 0, stream>>>(packed, dinv, cnt, csr + N_EDGES);
  const int nb = (N_NODES + 1023) / 1024;
  k_scan_partial<<<nb, 256, 0, stream>>>(cnt, bsum);
  k_scan_bsum<<<1, 64, 0, stream>>>(bsum, nb);
  k_scan_final<<<nb, 256, 0, stream>>>(cnt, bsum, offs);
  k_fill<<<N_EDGES / 256, 256, 0, stream>>>(ei, ew, rank, offs, csr);
  const int g1_waves = N_NODES / 16;                 // 6250
  k_gemm1<<<(g1_waves + 3) / 4, 256, 0, stream>>>(x, w1bf, dinv, h_u16);
  k_agg1<<<(N_NODES + 3) / 4, 256, 0, stream>>>((const unsigned*)h_u16, dinv, offs, cnt,
                                                csr, b1, act1_u);
  k_gemm2<<<N_NODES / 32, 256, 0, stream>>>(act1_u, W2, dinv, h2);
  k_agg2<<<N_NODES / 32, 256, 0, stream>>>(h2, dinv, offs, cnt, csr, b2, out);
}